// Round 1
// baseline (2174.194 us; speedup 1.0000x reference)
//
#include <hip/hip_runtime.h>
#include <cmath>

#define T_SEQ   1024
#define DMODEL  1024
#define DINNER  2048
#define DSTATE  64
#define NHEADS  32
#define HEADDIM 64
#define CONVDIM 2176
#define DPROJ   4256
#define DFF     4096
#define VOCAB   50257
#define CLEN    16
#define NCHUNK  64

typedef float f32x4 __attribute__((ext_vector_type(4)));
typedef unsigned short u16;
typedef u16 u16x4 __attribute__((ext_vector_type(4)));
typedef u16 u16x8 __attribute__((ext_vector_type(8)));
typedef __bf16 bf16x8 __attribute__((ext_vector_type(8)));

__device__ __forceinline__ u16 f2bf(float f) {
  unsigned u = __builtin_bit_cast(unsigned, f);
  u += 0x7FFFu + ((u >> 16) & 1u);
  return (u16)(u >> 16);
}
__device__ __forceinline__ float silu_f(float x) { return x / (1.f + expf(-x)); }

// ---------------------------------------------------------------- GEMM
// C[m,n] = sum_k A[m,k] * B[n,k]   (A: MxK row-major, B: NxK row-major = W)
// optional residual add. f32 in/out, bf16 MFMA internally.
__global__ __launch_bounds__(256) void gemm_bt(
    const float* __restrict__ A, const float* __restrict__ B,
    float* __restrict__ C, const float* __restrict__ res,
    int M, int N, int K)
{
  __shared__ u16 As[128 * 40];
  __shared__ u16 Bs[128 * 40];
  const int tid = threadIdx.x;
  const int m0 = blockIdx.y << 7;
  const int n0 = blockIdx.x << 7;
  const int lane = tid & 63;
  const int wid = tid >> 6;
  const int wm = (wid >> 1) << 6;
  const int wn = (wid & 1) << 6;
  const int lr = lane & 15;
  const int kg = lane >> 4;

  const int r4 = (tid >> 3) << 2;   // staging rows r4..r4+3
  const int c4 = (tid & 7) << 2;    // staging col (floats)

  const float* Ap = A + (size_t)(m0 + r4) * K + c4;
  const float* Bp = B + (size_t)(n0 + r4) * K + c4;
  bool bv[4];
#pragma unroll
  for (int j = 0; j < 4; ++j) bv[j] = (n0 + r4 + j) < N;

  f32x4 acc[4][4];
#pragma unroll
  for (int i = 0; i < 4; ++i)
#pragma unroll
    for (int j = 0; j < 4; ++j) acc[i][j] = (f32x4){0.f, 0.f, 0.f, 0.f};

  for (int k0 = 0; k0 < K; k0 += 32) {
#pragma unroll
    for (int j = 0; j < 4; ++j) {
      f32x4 av = *(const f32x4*)(Ap + (size_t)j * K + k0);
      f32x4 bw = bv[j] ? *(const f32x4*)(Bp + (size_t)j * K + k0)
                       : (f32x4){0.f, 0.f, 0.f, 0.f};
      u16x4 au = { f2bf(av[0]), f2bf(av[1]), f2bf(av[2]), f2bf(av[3]) };
      u16x4 bu = { f2bf(bw[0]), f2bf(bw[1]), f2bf(bw[2]), f2bf(bw[3]) };
      *(u16x4*)&As[(r4 + j) * 40 + c4] = au;
      *(u16x4*)&Bs[(r4 + j) * 40 + c4] = bu;
    }
    __syncthreads();
    bf16x8 af[4], bfr[4];
#pragma unroll
    for (int f = 0; f < 4; ++f) {
      af[f]  = __builtin_bit_cast(bf16x8, *(const u16x8*)&As[(wm + f * 16 + lr) * 40 + kg * 8]);
      bfr[f] = __builtin_bit_cast(bf16x8, *(const u16x8*)&Bs[(wn + f * 16 + lr) * 40 + kg * 8]);
    }
#pragma unroll
    for (int i = 0; i < 4; ++i)
#pragma unroll
      for (int j = 0; j < 4; ++j)
        acc[i][j] = __builtin_amdgcn_mfma_f32_16x16x32_bf16(af[i], bfr[j], acc[i][j], 0, 0, 0);
    __syncthreads();
  }

  const int mr = (lane >> 4) << 2;
  const int nc = lane & 15;
#pragma unroll
  for (int i = 0; i < 4; ++i) {
#pragma unroll
    for (int j = 0; j < 4; ++j) {
      int n = n0 + wn + j * 16 + nc;
      if (n < N) {
#pragma unroll
        for (int e = 0; e < 4; ++e) {
          size_t off = (size_t)(m0 + wm + i * 16 + mr + e) * N + n;
          float v = acc[i][j][e];
          if (res) v += res[off];
          C[off] = v;
        }
      }
    }
  }
}

// ---------------------------------------------------------------- elementwise
__global__ void k_embed(const int* __restrict__ idx, const float* __restrict__ E,
                        float* __restrict__ h) {
  int gi = blockIdx.x * 256 + threadIdx.x;  // 1024*1024
  int t = gi >> 10, d = gi & 1023;
  h[gi] = E[(size_t)idx[t] * DMODEL + d];
}

__global__ void k_layernorm(const float* __restrict__ in, const float* __restrict__ w,
                            float* __restrict__ out) {
  int t = blockIdx.x, tid = threadIdx.x;
  float x[4], s = 0.f, sq = 0.f;
#pragma unroll
  for (int i = 0; i < 4; ++i) {
    x[i] = in[(size_t)t * 1024 + tid + i * 256];
    s += x[i]; sq += x[i] * x[i];
  }
#pragma unroll
  for (int o = 32; o; o >>= 1) { s += __shfl_down(s, o); sq += __shfl_down(sq, o); }
  __shared__ float sb[4], qb[4];
  if ((tid & 63) == 0) { sb[tid >> 6] = s; qb[tid >> 6] = sq; }
  __syncthreads();
  s = sb[0] + sb[1] + sb[2] + sb[3];
  sq = qb[0] + qb[1] + qb[2] + qb[3];
  float mu = s * (1.f / 1024.f);
  float var = sq * (1.f / 1024.f) - mu * mu;
  float rstd = rsqrtf(var + 1e-5f);
#pragma unroll
  for (int i = 0; i < 4; ++i) {
    int j = tid + i * 256;
    out[(size_t)t * 1024 + j] = (x[i] - mu) * rstd * w[j];
  }
}

__global__ void k_conv(const float* __restrict__ zx, const float* __restrict__ cw,
                       const float* __restrict__ cb, float* __restrict__ xbc) {
  int c = blockIdx.x * 256 + threadIdx.x;
  int t = blockIdx.y;
  if (c >= CONVDIM) return;
  float acc = cb[c];
#pragma unroll
  for (int k = 0; k < 4; ++k) {
    int tt = t + k - 3;
    if (tt >= 0) acc += zx[(size_t)tt * DPROJ + 2048 + c] * cw[c * 4 + k];
  }
  xbc[(size_t)t * CONVDIM + c] = silu_f(acc);
}

__global__ void k_dtda(const float* __restrict__ zx, const float* __restrict__ dtb,
                       const float* __restrict__ alog, float* __restrict__ dtsp,
                       float* __restrict__ dag) {
  int gi = blockIdx.x * 256 + threadIdx.x;  // 1024*32
  int t = gi >> 5, hh = gi & 31;
  float raw = zx[(size_t)t * DPROJ + 4224 + hh] + dtb[hh];
  float sp = raw > 20.f ? raw : log1pf(expf(raw));
  dtsp[gi] = sp;
  dag[gi] = expf(-expf(alog[hh]) * sp);
}

__global__ void k_prefix(const float* __restrict__ dag, float* __restrict__ pref,
                         float* __restrict__ dacum) {
  int gi = blockIdx.x * 256 + threadIdx.x;  // 64*32
  int c = gi >> 5, hh = gi & 31;
  float P = 1.f;
  for (int s_ = 0; s_ < CLEN; ++s_) {
    int t = c * CLEN + s_;
    P *= dag[t * 32 + hh];
    pref[t * 32 + hh] = P;
  }
  dacum[gi] = P;
}

// ---------------------------------------------------------------- chunked scan
// pass A: per (chunk, head): local scan from zero state; y_local; S_local.
__global__ __launch_bounds__(256) void k_scan_local(
    const float* __restrict__ xbc, const float* __restrict__ dtsp,
    const float* __restrict__ dag, float* __restrict__ yb, float* __restrict__ Sloc)
{
  int c = blockIdx.x, hh = blockIdx.y;
  int tid = threadIdx.x;
  int p = tid >> 2, ng = tid & 3, n0 = ng << 4;
  float st[16];
#pragma unroll
  for (int j = 0; j < 16; ++j) st[j] = 0.f;
  for (int s_ = 0; s_ < CLEN; ++s_) {
    int t = c * CLEN + s_;
    float dA = dag[t * 32 + hh];
    float coef = dtsp[t * 32 + hh] * xbc[(size_t)t * CONVDIM + hh * 64 + p];
    const f32x4* B4 = (const f32x4*)&xbc[(size_t)t * CONVDIM + 2048 + n0];
    const f32x4* C4 = (const f32x4*)&xbc[(size_t)t * CONVDIM + 2112 + n0];
    float y = 0.f;
#pragma unroll
    for (int q = 0; q < 4; ++q) {
      f32x4 b = B4[q], cc = C4[q];
#pragma unroll
      for (int e = 0; e < 4; ++e) {
        int j = q * 4 + e;
        st[j] = dA * st[j] + coef * b[e];
        y += st[j] * cc[e];
      }
    }
    y += __shfl_xor(y, 1);
    y += __shfl_xor(y, 2);
    if (ng == 0) yb[(size_t)t * DINNER + hh * 64 + p] = y;
  }
  float* Sp = Sloc + ((size_t)(c * 32 + hh) * 64 + p) * 64 + n0;
#pragma unroll
  for (int q = 0; q < 4; ++q)
    *(f32x4*)(Sp + q * 4) = (f32x4){ st[q*4], st[q*4+1], st[q*4+2], st[q*4+3] };
}

// pass B: sequential over 64 chunks, parallel over (h,p,n); writes incoming state per chunk.
__global__ void k_chain(const float* __restrict__ Sloc, const float* __restrict__ dacum,
                        float* __restrict__ Sin) {
  int e = blockIdx.x * 256 + threadIdx.x;  // 131072
  int hh = e >> 12;
  float S = 0.f;
  for (int c = 0; c < NCHUNK; ++c) {
    Sin[(size_t)c * 131072 + e] = S;
    S = dacum[c * 32 + hh] * S + Sloc[(size_t)c * 131072 + e];
  }
}

// pass C: y[t,h,p] = y_local + prefix * (C_t . S_in) + Dp*x
__global__ __launch_bounds__(256) void k_scan_fix(
    const float* __restrict__ xbc, const float* __restrict__ pref,
    const float* __restrict__ Sin, const float* __restrict__ Dp,
    float* __restrict__ yb)
{
  __shared__ float Sl[64 * 68];
  int c = blockIdx.x, hh = blockIdx.y;
  int tid = threadIdx.x;
  for (int i = 0; i < 16; ++i) {
    int e = i * 256 + tid;
    Sl[(e >> 6) * 68 + (e & 63)] = Sin[(size_t)(c * 32 + hh) * 4096 + e];
  }
  __syncthreads();
  int p = tid >> 2, ng = tid & 3, n0 = ng << 4;
  float Dh = Dp[hh];
  for (int s_ = 0; s_ < CLEN; ++s_) {
    int t = c * CLEN + s_;
    const f32x4* C4 = (const f32x4*)&xbc[(size_t)t * CONVDIM + 2112 + n0];
    float yc = 0.f;
#pragma unroll
    for (int q = 0; q < 4; ++q) {
      f32x4 cc = C4[q];
#pragma unroll
      for (int e = 0; e < 4; ++e) yc += Sl[p * 68 + n0 + q * 4 + e] * cc[e];
    }
    yc += __shfl_xor(yc, 1);
    yc += __shfl_xor(yc, 2);
    if (ng == 0) {
      size_t oy = (size_t)t * DINNER + hh * 64 + p;
      yb[oy] = yb[oy] + pref[t * 32 + hh] * yc + Dh * xbc[(size_t)t * CONVDIM + hh * 64 + p];
    }
  }
}

__global__ void k_gated_rms(const float* __restrict__ yb, const float* __restrict__ zx,
                            const float* __restrict__ gw, float* __restrict__ out) {
  int t = blockIdx.x, tid = threadIdx.x;
  float v[8], ss = 0.f;
#pragma unroll
  for (int i = 0; i < 8; ++i) {
    int j = tid + i * 256;
    float z = zx[(size_t)t * DPROJ + j];
    float vv = yb[(size_t)t * DINNER + j] * silu_f(z);
    v[i] = vv; ss += vv * vv;
  }
#pragma unroll
  for (int o = 32; o; o >>= 1) ss += __shfl_down(ss, o);
  __shared__ float sb[4];
  if ((tid & 63) == 0) sb[tid >> 6] = ss;
  __syncthreads();
  ss = sb[0] + sb[1] + sb[2] + sb[3];
  float rstd = rsqrtf(ss * (1.f / 2048.f) + 1e-5f);
#pragma unroll
  for (int i = 0; i < 8; ++i) {
    int j = tid + i * 256;
    out[(size_t)t * DINNER + j] = v[i] * rstd * gw[j];
  }
}

__global__ void k_glu(const float* __restrict__ fc1, float* __restrict__ out) {
  int gi = blockIdx.x * 256 + threadIdx.x;  // 1024*4096
  int t = gi >> 12, j = gi & 4095;
  float y = fc1[(size_t)t * 8192 + j];
  float g = fc1[(size_t)t * 8192 + 4096 + j];
  out[gi] = y * silu_f(g);
}

// ---------------------------------------------------------------- loss
__global__ void k_loss_row(const float* __restrict__ logits, const int* __restrict__ tgt,
                           float* __restrict__ part) {
  int t = blockIdx.x, tid = threadIdx.x;
  float m = -1e30f, s = 0.f;
  for (int j = tid; j < VOCAB; j += 256) {
    float x = logits[(size_t)t * VOCAB + j];
    if (x > m) { s = s * expf(m - x) + 1.f; m = x; }
    else s += expf(x - m);
  }
#pragma unroll
  for (int o = 32; o; o >>= 1) {
    float m2 = __shfl_down(m, o), s2 = __shfl_down(s, o);
    float M = fmaxf(m, m2);
    s = s * expf(m - M) + s2 * expf(m2 - M);
    m = M;
  }
  __shared__ float ms[4], ssh[4];
  if ((tid & 63) == 0) { ms[tid >> 6] = m; ssh[tid >> 6] = s; }
  __syncthreads();
  if (tid == 0) {
    float M = ms[0], S = ssh[0];
    for (int w = 1; w < 4; ++w) {
      float M2 = fmaxf(M, ms[w]);
      S = S * expf(M - M2) + ssh[w] * expf(ms[w] - M2);
      M = M2;
    }
    float lse = M + logf(S);
    part[t] = lse - logits[(size_t)t * VOCAB + tgt[t]];
  }
}

__global__ void k_loss_mean(const float* __restrict__ part, float* __restrict__ out) {
  int tid = threadIdx.x;
  float s = 0.f;
  for (int j = tid; j < 1024; j += 256) s += part[j];
#pragma unroll
  for (int o = 32; o; o >>= 1) s += __shfl_down(s, o);
  __shared__ float sb[4];
  if ((tid & 63) == 0) sb[tid >> 6] = s;
  __syncthreads();
  if (tid == 0) out[0] = (sb[0] + sb[1] + sb[2] + sb[3]) * (1.f / 1024.f);
}

// ---------------------------------------------------------------- launch
extern "C" void kernel_launch(void* const* d_in, const int* in_sizes, int n_in,
                              void* d_out, int out_size, void* d_ws, size_t ws_size,
                              hipStream_t stream)
{
  const int*   idx       = (const int*)d_in[0];
  const int*   tgt       = (const int*)d_in[1];
  const float* E         = (const float*)d_in[2];
  const float* norm_w    = (const float*)d_in[3];
  const float* norm2_w   = (const float*)d_in[4];
  const float* in_proj_w = (const float*)d_in[5];
  const float* conv_w    = (const float*)d_in[6];
  const float* conv_b    = (const float*)d_in[7];
  const float* dt_bias   = (const float*)d_in[8];
  const float* A_log     = (const float*)d_in[9];
  const float* Dp        = (const float*)d_in[10];
  const float* gnorm_w   = (const float*)d_in[11];
  const float* out_proj_w= (const float*)d_in[12];
  const float* fc1_w     = (const float*)d_in[13];
  const float* fc2_w     = (const float*)d_in[14];
  const float* norm_f_w  = (const float*)d_in[15];
  float* logits = (float*)d_out;

  float* ws = (float*)d_ws;
  size_t off = 0;
  auto alloc = [&](size_t n) { float* p = ws + off; off += (n + 63) & ~(size_t)63; return p; };
  float* hbuf  = alloc((size_t)1024 * 1024);
  float* xnorm = alloc((size_t)1024 * 1024);
  float* big0  = alloc((size_t)1024 * 8192);   // zxbcdt (first 4.36M) / fc1 out
  float* xbc   = alloc((size_t)1024 * CONVDIM);
  float* dtsp  = alloc((size_t)1024 * 32);
  float* dag   = alloc((size_t)1024 * 32);
  float* pref  = alloc((size_t)1024 * 32);
  float* dacum = alloc((size_t)64 * 32);
  float* yb    = alloc((size_t)1024 * DINNER);
  float* Sloc  = alloc((size_t)64 * 32 * 64 * 64);
  float* Sin   = alloc((size_t)64 * 32 * 64 * 64);
  float* gated = alloc((size_t)1024 * DINNER);
  float* glu   = alloc((size_t)1024 * DFF);
  float* lpart = alloc((size_t)1024);
  (void)ws_size; (void)in_sizes; (void)n_in; (void)out_size;

  dim3 b256(256);

  k_embed<<<4096, b256, 0, stream>>>(idx, E, hbuf);

  for (int L = 0; L < 2; ++L) {
    k_layernorm<<<1024, b256, 0, stream>>>(hbuf, norm_w + L * 1024, xnorm);
    gemm_bt<<<dim3(34, 8), b256, 0, stream>>>(
        xnorm, in_proj_w + (size_t)L * DPROJ * 1024, big0, nullptr, 1024, DPROJ, 1024);
    k_conv<<<dim3(9, 1024), b256, 0, stream>>>(big0, conv_w + L * CONVDIM * 4, conv_b + L * CONVDIM, xbc);
    k_dtda<<<128, b256, 0, stream>>>(big0, dt_bias + L * 32, A_log + L * 32, dtsp, dag);
    k_prefix<<<8, b256, 0, stream>>>(dag, pref, dacum);
    k_scan_local<<<dim3(64, 32), b256, 0, stream>>>(xbc, dtsp, dag, yb, Sloc);
    k_chain<<<512, b256, 0, stream>>>(Sloc, dacum, Sin);
    k_scan_fix<<<dim3(64, 32), b256, 0, stream>>>(xbc, pref, Sin, Dp + L * 32, yb);
    k_gated_rms<<<1024, b256, 0, stream>>>(yb, big0, gnorm_w + L * 2048, gated);
    gemm_bt<<<dim3(8, 8), b256, 0, stream>>>(
        gated, out_proj_w + (size_t)L * 1024 * 2048, hbuf, hbuf, 1024, 1024, 2048);
    k_layernorm<<<1024, b256, 0, stream>>>(hbuf, norm2_w + L * 1024, xnorm);
    gemm_bt<<<dim3(64, 8), b256, 0, stream>>>(
        xnorm, fc1_w + (size_t)L * 8192 * 1024, big0, nullptr, 1024, 8192, 1024);
    k_glu<<<16384, b256, 0, stream>>>(big0, glu);
    gemm_bt<<<dim3(8, 8), b256, 0, stream>>>(
        glu, fc2_w + (size_t)L * 1024 * 4096, hbuf, hbuf, 1024, 1024, 4096);
  }

  k_layernorm<<<1024, b256, 0, stream>>>(hbuf, norm_f_w, xnorm);
  gemm_bt<<<dim3(393, 8), b256, 0, stream>>>(xnorm, E, logits, nullptr, 1024, VOCAB, 1024);
  k_loss_row<<<1024, b256, 0, stream>>>(logits, tgt, lpart);
  k_loss_mean<<<1, b256, 0, stream>>>(lpart, logits + (size_t)1024 * VOCAB);
}

// Round 2
// 990.098 us; speedup vs baseline: 2.1959x; 2.1959x over previous
//
#include <hip/hip_runtime.h>
#include <cmath>

#define T_SEQ   1024
#define DMODEL  1024
#define DINNER  2048
#define DSTATE  64
#define NHEADS  32
#define HEADDIM 64
#define CONVDIM 2176
#define DPROJ   4256
#define DFF     4096
#define VOCAB   50257
#define VOCABP  50304
#define CLEN    16
#define NCHUNK  64

typedef float f32x4 __attribute__((ext_vector_type(4)));
typedef unsigned short u16;
typedef u16 u16x8 __attribute__((ext_vector_type(8)));
typedef __bf16 bf16x8 __attribute__((ext_vector_type(8)));

__device__ __forceinline__ u16 f2bf(float f) {
  unsigned u = __builtin_bit_cast(unsigned, f);
  u += 0x7FFFu + ((u >> 16) & 1u);
  return (u16)(u >> 16);
}
__device__ __forceinline__ float silu_f(float x) { return x / (1.f + expf(-x)); }

__device__ __forceinline__ void gload16(const u16* g, u16* l) {
  __builtin_amdgcn_global_load_lds(
      (const __attribute__((address_space(1))) void*)g,
      (__attribute__((address_space(3))) void*)l,
      16, 0, 0);
}

// ---------------------------------------------------------------- bf16 GEMM
// C[m,n] = sum_k A[m,k]*B[n,k]; A: 1024xK bf16, B: NpadxK bf16 (rows padded
// to x128 with zeros). m97 structure: 128x128 tile, BK=32, global_load_lds x16.
// gridDim.z = split-K slices (kslice = K/slices); slice s writes C + s*1024*N.
__global__ __launch_bounds__(256) void gemm_bf16(
    const u16* __restrict__ A, const u16* __restrict__ B,
    float* __restrict__ C, const float* __restrict__ res,
    int N, int K, int kslice)
{
  __shared__ alignas(128) u16 As[128 * 32];
  __shared__ alignas(128) u16 Bs[128 * 32];
  const int tid = threadIdx.x;
  const int m0 = blockIdx.y << 7;
  const int n0 = blockIdx.x << 7;
  const int lane = tid & 63, wid = tid >> 6;
  const int wm = (wid >> 1) << 6, wn = (wid & 1) << 6;
  const int lr = lane & 15, kg = lane >> 4;

  // staging map: issue i, lane l -> LDS byte i*4096 + wid*1024 + l*16
  const int srow = wid * 16 + (lane >> 2);      // + i*64
  const int scol = (lane & 3) << 3;             // bf16 elems
  const u16* gA = A + (size_t)(m0 + srow) * K + scol;
  const u16* gB = B + (size_t)(n0 + srow) * K + scol;
  u16* lA = As + wid * 512 + 0;                 // wave-uniform base (+i*2048)
  u16* lB = Bs + wid * 512 + 0;

  f32x4 acc[4][4];
#pragma unroll
  for (int i = 0; i < 4; ++i)
#pragma unroll
    for (int j = 0; j < 4; ++j) acc[i][j] = (f32x4){0.f, 0.f, 0.f, 0.f};

  const int kb = blockIdx.z * kslice;
  const int ke = kb + kslice;
  for (int k0 = kb; k0 < ke; k0 += 32) {
    gload16(gA + k0, lA);
    gload16(gA + (size_t)64 * K + k0, lA + 2048);
    gload16(gB + k0, lB);
    gload16(gB + (size_t)64 * K + k0, lB + 2048);
    __syncthreads();
    bf16x8 af[4], bfr[4];
#pragma unroll
    for (int f = 0; f < 4; ++f) {
      af[f]  = *(const bf16x8*)&As[(wm + f * 16 + lr) * 32 + kg * 8];
      bfr[f] = *(const bf16x8*)&Bs[(wn + f * 16 + lr) * 32 + kg * 8];
    }
#pragma unroll
    for (int i = 0; i < 4; ++i)
#pragma unroll
      for (int j = 0; j < 4; ++j)
        acc[i][j] = __builtin_amdgcn_mfma_f32_16x16x32_bf16(af[i], bfr[j], acc[i][j], 0, 0, 0);
    __syncthreads();
  }

  const int mr = (lane >> 4) << 2;
  const int nc = lane & 15;
  float* Cw = C;
  const float* rp = res;
  if (gridDim.z > 1) { Cw += (size_t)blockIdx.z * 1024 * N; rp = nullptr; }
#pragma unroll
  for (int i = 0; i < 4; ++i)
#pragma unroll
    for (int j = 0; j < 4; ++j) {
      int n = n0 + wn + j * 16 + nc;
      if (n < N) {
#pragma unroll
        for (int e = 0; e < 4; ++e) {
          size_t o = (size_t)(m0 + wm + i * 16 + mr + e) * N + n;
          float v = acc[i][j][e];
          if (rp) v += rp[o];
          Cw[o] = v;
        }
      }
    }
}

__global__ void k_splitred(const float* __restrict__ part, float* __restrict__ hb,
                           int MN4, int S) {
  int gi = blockIdx.x * 256 + threadIdx.x;
  if (gi >= MN4) return;
  f32x4 s = ((const f32x4*)part)[gi];
  for (int k = 1; k < S; ++k)
    s += ((const f32x4*)(part + (size_t)k * MN4 * 4))[gi];
  ((f32x4*)hb)[gi] += s;
}

// ---------------------------------------------------------------- conversions
__global__ void k_cvt8(const float* __restrict__ src, u16* __restrict__ dst, int n8) {
  int i = blockIdx.x * 256 + threadIdx.x;
  if (i >= n8) return;
  f32x4 a = ((const f32x4*)src)[i * 2];
  f32x4 b = ((const f32x4*)src)[i * 2 + 1];
  u16x8 o = { f2bf(a[0]), f2bf(a[1]), f2bf(a[2]), f2bf(a[3]),
              f2bf(b[0]), f2bf(b[1]), f2bf(b[2]), f2bf(b[3]) };
  ((u16x8*)dst)[i] = o;
}

// pads flat tail [srcN8, n8) with zeros (whole trailing rows)
__global__ void k_cvt8_pad(const float* __restrict__ src, u16* __restrict__ dst,
                           int n8, int srcN8) {
  int i = blockIdx.x * 256 + threadIdx.x;
  if (i >= n8) return;
  u16x8 o;
  if (i < srcN8) {
    f32x4 a = ((const f32x4*)src)[i * 2];
    f32x4 b = ((const f32x4*)src)[i * 2 + 1];
    o = (u16x8){ f2bf(a[0]), f2bf(a[1]), f2bf(a[2]), f2bf(a[3]),
                 f2bf(b[0]), f2bf(b[1]), f2bf(b[2]), f2bf(b[3]) };
  } else {
    o = (u16x8){0, 0, 0, 0, 0, 0, 0, 0};
  }
  ((u16x8*)dst)[i] = o;
}

// ---------------------------------------------------------------- elementwise
__global__ void k_embed(const int* __restrict__ idx, const float* __restrict__ E,
                        float* __restrict__ h) {
  int gi = blockIdx.x * 256 + threadIdx.x;  // 1024*1024
  int t = gi >> 10, d = gi & 1023;
  h[gi] = E[(size_t)idx[t] * DMODEL + d];
}

__global__ void k_layernorm(const float* __restrict__ in, const float* __restrict__ w,
                            u16* __restrict__ out) {
  int t = blockIdx.x, tid = threadIdx.x;
  float x[4], s = 0.f, sq = 0.f;
#pragma unroll
  for (int i = 0; i < 4; ++i) {
    x[i] = in[(size_t)t * 1024 + tid + i * 256];
    s += x[i]; sq += x[i] * x[i];
  }
#pragma unroll
  for (int o = 32; o; o >>= 1) { s += __shfl_down(s, o); sq += __shfl_down(sq, o); }
  __shared__ float sb[4], qb[4];
  if ((tid & 63) == 0) { sb[tid >> 6] = s; qb[tid >> 6] = sq; }
  __syncthreads();
  s = sb[0] + sb[1] + sb[2] + sb[3];
  sq = qb[0] + qb[1] + qb[2] + qb[3];
  float mu = s * (1.f / 1024.f);
  float var = sq * (1.f / 1024.f) - mu * mu;
  float rstd = rsqrtf(var + 1e-5f);
#pragma unroll
  for (int i = 0; i < 4; ++i) {
    int j = tid + i * 256;
    out[(size_t)t * 1024 + j] = f2bf((x[i] - mu) * rstd * w[j]);
  }
}

__global__ void k_conv(const float* __restrict__ zx, const float* __restrict__ cw,
                       const float* __restrict__ cb, float* __restrict__ xbc) {
  int c = blockIdx.x * 256 + threadIdx.x;
  int t = blockIdx.y;
  if (c >= CONVDIM) return;
  float acc = cb[c];
#pragma unroll
  for (int k = 0; k < 4; ++k) {
    int tt = t + k - 3;
    if (tt >= 0) acc += zx[(size_t)tt * DPROJ + 2048 + c] * cw[c * 4 + k];
  }
  xbc[(size_t)t * CONVDIM + c] = silu_f(acc);
}

__global__ void k_dtda(const float* __restrict__ zx, const float* __restrict__ dtb,
                       const float* __restrict__ alog, float* __restrict__ dtsp,
                       float* __restrict__ dag) {
  int gi = blockIdx.x * 256 + threadIdx.x;  // 1024*32
  int t = gi >> 5, hh = gi & 31;
  float raw = zx[(size_t)t * DPROJ + 4224 + hh] + dtb[hh];
  float sp = raw > 20.f ? raw : log1pf(expf(raw));
  dtsp[gi] = sp;
  dag[gi] = expf(-expf(alog[hh]) * sp);
}

__global__ void k_prefix(const float* __restrict__ dag, float* __restrict__ pref,
                         float* __restrict__ dacum) {
  int gi = blockIdx.x * 256 + threadIdx.x;  // 64*32
  int c = gi >> 5, hh = gi & 31;
  float P = 1.f;
  for (int s_ = 0; s_ < CLEN; ++s_) {
    int t = c * CLEN + s_;
    P *= dag[t * 32 + hh];
    pref[t * 32 + hh] = P;
  }
  dacum[gi] = P;
}

// ---------------------------------------------------------------- chunked scan
__global__ __launch_bounds__(256) void k_scan_local(
    const float* __restrict__ xbc, const float* __restrict__ dtsp,
    const float* __restrict__ dag, float* __restrict__ yb, float* __restrict__ Sloc)
{
  int c = blockIdx.x, hh = blockIdx.y;
  int tid = threadIdx.x;
  int p = tid >> 2, ng = tid & 3, n0 = ng << 4;
  float st[16];
#pragma unroll
  for (int j = 0; j < 16; ++j) st[j] = 0.f;
  for (int s_ = 0; s_ < CLEN; ++s_) {
    int t = c * CLEN + s_;
    float dA = dag[t * 32 + hh];
    float coef = dtsp[t * 32 + hh] * xbc[(size_t)t * CONVDIM + hh * 64 + p];
    const f32x4* B4 = (const f32x4*)&xbc[(size_t)t * CONVDIM + 2048 + n0];
    const f32x4* C4 = (const f32x4*)&xbc[(size_t)t * CONVDIM + 2112 + n0];
    float y = 0.f;
#pragma unroll
    for (int q = 0; q < 4; ++q) {
      f32x4 b = B4[q], cc = C4[q];
#pragma unroll
      for (int e = 0; e < 4; ++e) {
        int j = q * 4 + e;
        st[j] = dA * st[j] + coef * b[e];
        y += st[j] * cc[e];
      }
    }
    y += __shfl_xor(y, 1);
    y += __shfl_xor(y, 2);
    if (ng == 0) yb[(size_t)t * DINNER + hh * 64 + p] = y;
  }
  float* Sp = Sloc + ((size_t)(c * 32 + hh) * 64 + p) * 64 + n0;
#pragma unroll
  for (int q = 0; q < 4; ++q)
    *(f32x4*)(Sp + q * 4) = (f32x4){ st[q*4], st[q*4+1], st[q*4+2], st[q*4+3] };
}

__global__ void k_chain(const float* __restrict__ Sloc, const float* __restrict__ dacum,
                        float* __restrict__ Sin) {
  int e = blockIdx.x * 256 + threadIdx.x;  // 131072
  int hh = e >> 12;
  float S = 0.f;
  for (int c = 0; c < NCHUNK; ++c) {
    Sin[(size_t)c * 131072 + e] = S;
    S = dacum[c * 32 + hh] * S + Sloc[(size_t)c * 131072 + e];
  }
}

__global__ __launch_bounds__(256) void k_scan_fix(
    const float* __restrict__ xbc, const float* __restrict__ pref,
    const float* __restrict__ Sin, const float* __restrict__ Dp,
    float* __restrict__ yb)
{
  __shared__ float Sl[64 * 68];
  int c = blockIdx.x, hh = blockIdx.y;
  int tid = threadIdx.x;
  for (int i = 0; i < 16; ++i) {
    int e = i * 256 + tid;
    Sl[(e >> 6) * 68 + (e & 63)] = Sin[(size_t)(c * 32 + hh) * 4096 + e];
  }
  __syncthreads();
  int p = tid >> 2, ng = tid & 3, n0 = ng << 4;
  float Dh = Dp[hh];
  for (int s_ = 0; s_ < CLEN; ++s_) {
    int t = c * CLEN + s_;
    const f32x4* C4 = (const f32x4*)&xbc[(size_t)t * CONVDIM + 2112 + n0];
    float yc = 0.f;
#pragma unroll
    for (int q = 0; q < 4; ++q) {
      f32x4 cc = C4[q];
#pragma unroll
      for (int e = 0; e < 4; ++e) yc += Sl[p * 68 + n0 + q * 4 + e] * cc[e];
    }
    yc += __shfl_xor(yc, 1);
    yc += __shfl_xor(yc, 2);
    if (ng == 0) {
      size_t oy = (size_t)t * DINNER + hh * 64 + p;
      yb[oy] = yb[oy] + pref[t * 32 + hh] * yc + Dh * xbc[(size_t)t * CONVDIM + hh * 64 + p];
    }
  }
}

__global__ void k_gated_rms(const float* __restrict__ yb, const float* __restrict__ zx,
                            const float* __restrict__ gw, u16* __restrict__ out) {
  int t = blockIdx.x, tid = threadIdx.x;
  float v[8], ss = 0.f;
#pragma unroll
  for (int i = 0; i < 8; ++i) {
    int j = tid + i * 256;
    float z = zx[(size_t)t * DPROJ + j];
    float vv = yb[(size_t)t * DINNER + j] * silu_f(z);
    v[i] = vv; ss += vv * vv;
  }
#pragma unroll
  for (int o = 32; o; o >>= 1) ss += __shfl_down(ss, o);
  __shared__ float sb[4];
  if ((tid & 63) == 0) sb[tid >> 6] = ss;
  __syncthreads();
  ss = sb[0] + sb[1] + sb[2] + sb[3];
  float rstd = rsqrtf(ss * (1.f / 2048.f) + 1e-5f);
#pragma unroll
  for (int i = 0; i < 8; ++i) {
    int j = tid + i * 256;
    out[(size_t)t * DINNER + j] = f2bf(v[i] * rstd * gw[j]);
  }
}

__global__ void k_glu(const float* __restrict__ fc1, u16* __restrict__ out) {
  int gi = blockIdx.x * 256 + threadIdx.x;  // 1024*4096
  int t = gi >> 12, j = gi & 4095;
  float y = fc1[(size_t)t * 8192 + j];
  float g = fc1[(size_t)t * 8192 + 4096 + j];
  out[gi] = f2bf(y * silu_f(g));
}

// ---------------------------------------------------------------- loss
__global__ void k_loss_row(const float* __restrict__ logits, const int* __restrict__ tgt,
                           float* __restrict__ part) {
  int t = blockIdx.x, tid = threadIdx.x;
  float m = -1e30f, s = 0.f;
  for (int j = tid; j < VOCAB; j += 256) {
    float x = logits[(size_t)t * VOCAB + j];
    if (x > m) { s = s * expf(m - x) + 1.f; m = x; }
    else s += expf(x - m);
  }
#pragma unroll
  for (int o = 32; o; o >>= 1) {
    float m2 = __shfl_down(m, o), s2 = __shfl_down(s, o);
    float M = fmaxf(m, m2);
    s = s * expf(m - M) + s2 * expf(m2 - M);
    m = M;
  }
  __shared__ float ms[4], ssh[4];
  if ((tid & 63) == 0) { ms[tid >> 6] = m; ssh[tid >> 6] = s; }
  __syncthreads();
  if (tid == 0) {
    float M = ms[0], S = ssh[0];
    for (int w = 1; w < 4; ++w) {
      float M2 = fmaxf(M, ms[w]);
      S = S * expf(M - M2) + ssh[w] * expf(ms[w] - M2);
      M = M2;
    }
    float lse = M + logf(S);
    part[t] = lse - logits[(size_t)t * VOCAB + tgt[t]];
  }
}

__global__ void k_loss_mean(const float* __restrict__ part, float* __restrict__ out) {
  int tid = threadIdx.x;
  float s = 0.f;
  for (int j = tid; j < 1024; j += 256) s += part[j];
#pragma unroll
  for (int o = 32; o; o >>= 1) s += __shfl_down(s, o);
  __shared__ float sb[4];
  if ((tid & 63) == 0) sb[tid >> 6] = s;
  __syncthreads();
  if (tid == 0) out[0] = (sb[0] + sb[1] + sb[2] + sb[3]) * (1.f / 1024.f);
}

// ---------------------------------------------------------------- launch
extern "C" void kernel_launch(void* const* d_in, const int* in_sizes, int n_in,
                              void* d_out, int out_size, void* d_ws, size_t ws_size,
                              hipStream_t stream)
{
  const int*   idx       = (const int*)d_in[0];
  const int*   tgt       = (const int*)d_in[1];
  const float* E         = (const float*)d_in[2];
  const float* norm_w    = (const float*)d_in[3];
  const float* norm2_w   = (const float*)d_in[4];
  const float* in_proj_w = (const float*)d_in[5];
  const float* conv_w    = (const float*)d_in[6];
  const float* conv_b    = (const float*)d_in[7];
  const float* dt_bias   = (const float*)d_in[8];
  const float* A_log     = (const float*)d_in[9];
  const float* Dp        = (const float*)d_in[10];
  const float* gnorm_w   = (const float*)d_in[11];
  const float* out_proj_w= (const float*)d_in[12];
  const float* fc1_w     = (const float*)d_in[13];
  const float* fc2_w     = (const float*)d_in[14];
  const float* norm_f_w  = (const float*)d_in[15];
  float* logits = (float*)d_out;
  (void)in_sizes; (void)n_in; (void)out_size; (void)ws_size;

  char* W = (char*)d_ws;
  size_t off = 0;
  auto A8 = [&](size_t bytes) { void* p = W + off; off = (off + bytes + 255) & ~(size_t)255; return p; };
  float* hbuf   = (float*)A8((size_t)1024 * 1024 * 4);
  u16*   xnormb = (u16*)  A8((size_t)1024 * 1024 * 2);
  u16*   gatedb = (u16*)  A8((size_t)1024 * 2048 * 2);
  u16*   glub   = (u16*)  A8((size_t)1024 * 4096 * 2);
  float* dtsp   = (float*)A8((size_t)1024 * 32 * 4);
  float* dag    = (float*)A8((size_t)1024 * 32 * 4);
  float* pref   = (float*)A8((size_t)1024 * 32 * 4);
  float* dacum  = (float*)A8((size_t)2048 * 4);
  float* lpart  = (float*)A8((size_t)1024 * 4);
  u16*   wip    = (u16*)  A8((size_t)2 * 4352 * 1024 * 2);
  u16*   wop    = (u16*)  A8((size_t)2 * 1024 * 2048 * 2);
  u16*   wfc1   = (u16*)  A8((size_t)2 * 8192 * 1024 * 2);
  u16*   wfc2   = (u16*)  A8((size_t)2 * 1024 * 4096 * 2);
  // shared span: layer-temporaries overlap with E_bf (used only after layers)
  char*  span   = (char*)A8((size_t)120 * 1024 * 1024);
  float* big0   = (float*)(span);                                  // 32 MB (1024x8192)
  float* xbc    = (float*)(span + (size_t)33554432);               // 8.9 MB
  float* yb     = (float*)(span + (size_t)33554432 + 8912896);     // 8 MB
  float* Sloc   = (float*)(span + (size_t)33554432 + 8912896 + 8388608);   // 32 MB
  float* Sin    = (float*)((char*)Sloc + (size_t)33554432);        // 32 MB
  float* part   = Sloc;                                            // 16 MB alias
  u16*   Ebf    = (u16*)span;                                      // 103 MB alias

  dim3 b256(256);

  // weight conversions (bf16), padded where N % 128 != 0
  k_cvt8_pad<<<dim3((4352*1024/8 + 255)/256), b256, 0, stream>>>(
      in_proj_w, wip, 4352*1024/8, 4256*1024/8);
  k_cvt8_pad<<<dim3((4352*1024/8 + 255)/256), b256, 0, stream>>>(
      in_proj_w + (size_t)4256*1024, wip + (size_t)4352*1024, 4352*1024/8, 4256*1024/8);
  k_cvt8<<<dim3(2*1024*2048/8/256), b256, 0, stream>>>(out_proj_w, wop, 2*1024*2048/8);
  k_cvt8<<<dim3(2*8192*1024/8/256), b256, 0, stream>>>(fc1_w, wfc1, 2*8192*1024/8);
  k_cvt8<<<dim3(2*1024*4096/8/256), b256, 0, stream>>>(fc2_w, wfc2, 2*1024*4096/8);

  k_embed<<<4096, b256, 0, stream>>>(idx, E, hbuf);

  for (int L = 0; L < 2; ++L) {
    k_layernorm<<<1024, b256, 0, stream>>>(hbuf, norm_w + L * 1024, xnormb);
    gemm_bf16<<<dim3(34, 8, 1), b256, 0, stream>>>(
        xnormb, wip + (size_t)L * 4352 * 1024, big0, nullptr, DPROJ, 1024, 1024);
    k_conv<<<dim3(9, 1024), b256, 0, stream>>>(big0, conv_w + L * CONVDIM * 4, conv_b + L * CONVDIM, xbc);
    k_dtda<<<128, b256, 0, stream>>>(big0, dt_bias + L * 32, A_log + L * 32, dtsp, dag);
    k_prefix<<<8, b256, 0, stream>>>(dag, pref, dacum);
    k_scan_local<<<dim3(64, 32), b256, 0, stream>>>(xbc, dtsp, dag, yb, Sloc);
    k_chain<<<512, b256, 0, stream>>>(Sloc, dacum, Sin);
    k_scan_fix<<<dim3(64, 32), b256, 0, stream>>>(xbc, pref, Sin, Dp + L * 32, yb);
    k_gated_rms<<<1024, b256, 0, stream>>>(yb, big0, gnorm_w + L * 2048, gatedb);
    gemm_bf16<<<dim3(8, 8, 2), b256, 0, stream>>>(
        gatedb, wop + (size_t)L * 1024 * 2048, part, nullptr, 1024, 2048, 1024);
    k_splitred<<<1024, b256, 0, stream>>>(part, hbuf, 1024 * 1024 / 4, 2);
    k_layernorm<<<1024, b256, 0, stream>>>(hbuf, norm2_w + L * 1024, xnormb);
    gemm_bf16<<<dim3(64, 8, 1), b256, 0, stream>>>(
        xnormb, wfc1 + (size_t)L * 8192 * 1024, big0, nullptr, 8192, 1024, 1024);
    k_glu<<<16384, b256, 0, stream>>>(big0, glub);
    gemm_bf16<<<dim3(8, 8, 4), b256, 0, stream>>>(
        glub, wfc2 + (size_t)L * 1024 * 4096, part, nullptr, 1024, 4096, 1024);
    k_splitred<<<1024, b256, 0, stream>>>(part, hbuf, 1024 * 1024 / 4, 4);
  }

  // E -> bf16 (padded to 50304 rows) into the now-dead span
  k_cvt8_pad<<<dim3((VOCABP*1024/8 + 255)/256), b256, 0, stream>>>(
      E, Ebf, VOCABP*1024/8, VOCAB*1024/8);
  k_layernorm<<<1024, b256, 0, stream>>>(hbuf, norm_f_w, xnormb);
  gemm_bf16<<<dim3(393, 8, 1), b256, 0, stream>>>(
      xnormb, Ebf, logits, nullptr, VOCAB, 1024, 1024);
  k_loss_row<<<1024, b256, 0, stream>>>(logits, tgt, lpart);
  k_loss_mean<<<1, b256, 0, stream>>>(lpart, logits + (size_t)1024 * VOCAB);
}

// Round 3
// 928.253 us; speedup vs baseline: 2.3422x; 1.0666x over previous
//
#include <hip/hip_runtime.h>
#include <cmath>

#define DMODEL  1024
#define DINNER  2048
#define NHEADS  32
#define CONVDIM 2176
#define DPROJ   4256
#define VOCAB   50257
#define VOCABP  50304
#define CLEN    16
#define NCHUNK  64

typedef float f32x4 __attribute__((ext_vector_type(4)));
typedef float f32x2 __attribute__((ext_vector_type(2)));
typedef unsigned short u16;
typedef u16 u16x4 __attribute__((ext_vector_type(4)));
typedef u16 u16x8 __attribute__((ext_vector_type(8)));
typedef __bf16 bf16x8 __attribute__((ext_vector_type(8)));

__device__ __forceinline__ u16 f2bf(float f) {
  unsigned u = __builtin_bit_cast(unsigned, f);
  u += 0x7FFFu + ((u >> 16) & 1u);
  return (u16)(u >> 16);
}
__device__ __forceinline__ float silu_f(float x) { return x / (1.f + expf(-x)); }

__device__ __forceinline__ void gload16(const u16* g, u16* l) {
  __builtin_amdgcn_global_load_lds(
      (const __attribute__((address_space(1))) void*)g,
      (__attribute__((address_space(3))) void*)l,
      16, 0, 0);
}

// ---------------------------------------------------------------- bf16 GEMM
// C[m,n] = sum_k A[m,k]*B[n,k]. A: 1024xK bf16. B: NpadxK bf16 (rows padded
// to x128). BK=64, 128x128 tile. blockIdx.x = m-block (8, fastest -> B-tile
// L2/L3 reuse), blockIdx.y = n-block, blockIdx.z = split-K slice.
// lsepart != null: also emit per-(row, n-block) online-softmax partials.
__global__ __launch_bounds__(256) void gemm_bf16(
    const u16* __restrict__ A, const u16* __restrict__ B,
    float* __restrict__ C, int N, int K, int kslice,
    float* __restrict__ lsepart)
{
  __shared__ alignas(128) u16 As[128 * 64];
  __shared__ alignas(128) u16 Bs[128 * 64];
  const int tid = threadIdx.x;
  const int m0 = blockIdx.x << 7;
  const int n0 = blockIdx.y << 7;
  const int lane = tid & 63, wid = tid >> 6;
  const int wm = (wid >> 1) << 6, wn = (wid & 1) << 6;
  const int lr = lane & 15, kg = lane >> 4;

  // staging: issue i, wave w, lane l -> LDS u16 idx i*2048+w*512+l*8
  //   = row (i*32 + w*8 + (l>>3)), col (l&7)*8
  const int srow = wid * 8 + (lane >> 3);
  const int scol = (lane & 7) << 3;
  const u16* gA = A + (size_t)(m0 + srow) * K + scol;
  const u16* gB = B + (size_t)(n0 + srow) * K + scol;

  f32x4 acc[4][4];
#pragma unroll
  for (int i = 0; i < 4; ++i)
#pragma unroll
    for (int j = 0; j < 4; ++j) acc[i][j] = (f32x4){0.f, 0.f, 0.f, 0.f};

  const int kb = blockIdx.z * kslice;
  const int ke = kb + kslice;
  for (int k0 = kb; k0 < ke; k0 += 64) {
#pragma unroll
    for (int i = 0; i < 4; ++i) {
      gload16(gA + k0 + (size_t)i * 32 * K, As + i * 2048 + wid * 512);
      gload16(gB + k0 + (size_t)i * 32 * K, Bs + i * 2048 + wid * 512);
    }
    __syncthreads();
#pragma unroll
    for (int kk = 0; kk < 2; ++kk) {
      bf16x8 af[4], bfr[4];
#pragma unroll
      for (int f = 0; f < 4; ++f) {
        af[f]  = *(const bf16x8*)&As[(wm + f * 16 + lr) * 64 + kk * 32 + kg * 8];
        bfr[f] = *(const bf16x8*)&Bs[(wn + f * 16 + lr) * 64 + kk * 32 + kg * 8];
      }
#pragma unroll
      for (int i = 0; i < 4; ++i)
#pragma unroll
        for (int j = 0; j < 4; ++j)
          acc[i][j] = __builtin_amdgcn_mfma_f32_16x16x32_bf16(af[i], bfr[j], acc[i][j], 0, 0, 0);
    }
    __syncthreads();
  }

  const int mr = (lane >> 4) << 2;
  const int nc = lane & 15;
  float* Cw = C + (gridDim.z > 1 ? (size_t)blockIdx.z * 1024 * N : 0);
#pragma unroll
  for (int i = 0; i < 4; ++i)
#pragma unroll
    for (int j = 0; j < 4; ++j) {
      int n = n0 + wn + j * 16 + nc;
      if (n < N) {
#pragma unroll
        for (int e = 0; e < 4; ++e)
          Cw[(size_t)(m0 + wm + i * 16 + mr + e) * N + n] = acc[i][j][e];
      }
    }

  if (lsepart) {
    float* Ls = (float*)As;  // [128 rows][2 halves][2]
#pragma unroll
    for (int i = 0; i < 4; ++i)
#pragma unroll
      for (int e = 0; e < 4; ++e) {
        float pm = -1e30f;
#pragma unroll
        for (int j = 0; j < 4; ++j) {
          int n = n0 + wn + j * 16 + nc;
          if (n < N) pm = fmaxf(pm, acc[i][j][e]);
        }
        float ps = 0.f;
#pragma unroll
        for (int j = 0; j < 4; ++j) {
          int n = n0 + wn + j * 16 + nc;
          if (n < N) ps += expf(acc[i][j][e] - pm);
        }
#pragma unroll
        for (int o = 1; o < 16; o <<= 1) {
          float pm2 = __shfl_xor(pm, o), ps2 = __shfl_xor(ps, o);
          float M = fmaxf(pm, pm2);
          ps = ps * expf(pm - M) + ps2 * expf(pm2 - M);
          pm = M;
        }
        if (nc == 0) {
          int row = wm + i * 16 + mr + e;
          Ls[row * 4 + (wid & 1) * 2] = pm;
          Ls[row * 4 + (wid & 1) * 2 + 1] = ps;
        }
      }
    __syncthreads();
    if (tid < 128) {
      float pa = Ls[tid * 4], sa = Ls[tid * 4 + 1];
      float pb = Ls[tid * 4 + 2], sb = Ls[tid * 4 + 3];
      float M = fmaxf(pa, pb);
      float S = sa * expf(pa - M) + sb * expf(pb - M);
      ((f32x2*)lsepart)[(size_t)(m0 + tid) * gridDim.y + blockIdx.y] = (f32x2){M, S};
    }
  }
}

// ---------------------------------------------------------------- conversions
__global__ void k_cvt8(const float* __restrict__ src, u16* __restrict__ dst, int n8) {
  int i = blockIdx.x * 256 + threadIdx.x;
  if (i >= n8) return;
  f32x4 a = ((const f32x4*)src)[i * 2];
  f32x4 b = ((const f32x4*)src)[i * 2 + 1];
  u16x8 o = { f2bf(a[0]), f2bf(a[1]), f2bf(a[2]), f2bf(a[3]),
              f2bf(b[0]), f2bf(b[1]), f2bf(b[2]), f2bf(b[3]) };
  ((u16x8*)dst)[i] = o;
}

__global__ void k_cvt8_pad(const float* __restrict__ src, u16* __restrict__ dst,
                           int n8, int srcN8) {
  int i = blockIdx.x * 256 + threadIdx.x;
  if (i >= n8) return;
  u16x8 o;
  if (i < srcN8) {
    f32x4 a = ((const f32x4*)src)[i * 2];
    f32x4 b = ((const f32x4*)src)[i * 2 + 1];
    o = (u16x8){ f2bf(a[0]), f2bf(a[1]), f2bf(a[2]), f2bf(a[3]),
                 f2bf(b[0]), f2bf(b[1]), f2bf(b[2]), f2bf(b[3]) };
  } else {
    o = (u16x8){0, 0, 0, 0, 0, 0, 0, 0};
  }
  ((u16x8*)dst)[i] = o;
}

// ---------------------------------------------------------------- fused LN
__device__ __forceinline__ void ln_write(f32x4 v, const float* __restrict__ w,
                                         u16* __restrict__ out, int t, int tid) {
  float s = v[0] + v[1] + v[2] + v[3];
  float sq = v[0]*v[0] + v[1]*v[1] + v[2]*v[2] + v[3]*v[3];
#pragma unroll
  for (int o = 32; o; o >>= 1) { s += __shfl_down(s, o); sq += __shfl_down(sq, o); }
  __shared__ float sb[4], qb[4];
  if ((tid & 63) == 0) { sb[tid >> 6] = s; qb[tid >> 6] = sq; }
  __syncthreads();
  s = sb[0] + sb[1] + sb[2] + sb[3];
  sq = qb[0] + qb[1] + qb[2] + qb[3];
  float mu = s * (1.f / 1024.f);
  float rstd = rsqrtf(sq * (1.f / 1024.f) - mu * mu + 1e-5f);
  u16x4 o;
#pragma unroll
  for (int e = 0; e < 4; ++e) o[e] = f2bf((v[e] - mu) * rstd * w[tid * 4 + e]);
  ((u16x4*)out)[t * 256 + tid] = o;
}

__global__ void k_ln_embed(const int* __restrict__ idx, const float* __restrict__ E,
                           const float* __restrict__ w, float* __restrict__ hbuf,
                           u16* __restrict__ out) {
  int t = blockIdx.x, tid = threadIdx.x;
  f32x4 v = ((const f32x4*)(E + (size_t)idx[t] * DMODEL))[tid];
  ((f32x4*)hbuf)[t * 256 + tid] = v;
  ln_write(v, w, out, t, tid);
}

// splitK reduce + residual accumulate + LN -> bf16
__global__ void k_red_ln(const float* __restrict__ part, int S,
                         float* __restrict__ hbuf, const float* __restrict__ w,
                         u16* __restrict__ out) {
  int t = blockIdx.x, tid = threadIdx.x;
  f32x4 v = ((const f32x4*)hbuf)[t * 256 + tid];
  for (int k = 0; k < S; ++k)
    v += ((const f32x4*)part)[(size_t)k * 262144 + t * 256 + tid];
  ((f32x4*)hbuf)[t * 256 + tid] = v;
  ln_write(v, w, out, t, tid);
}

// ---------------------------------------------------------------- conv + dt
__global__ void k_convdt(const float* __restrict__ zx, const float* __restrict__ cw,
                         const float* __restrict__ cb, const float* __restrict__ dtb,
                         const float* __restrict__ alog, float* __restrict__ xbc,
                         float* __restrict__ dtsp, float* __restrict__ dag) {
  int t = blockIdx.y, x = blockIdx.x, tid = threadIdx.x;
  if (x < 8 || tid < 128) {
    int c = x * 256 + tid;
    float acc = cb[c];
#pragma unroll
    for (int k = 0; k < 4; ++k) {
      int tt = t + k - 3;
      if (tt >= 0) acc += zx[(size_t)tt * DPROJ + 2048 + c] * cw[c * 4 + k];
    }
    xbc[(size_t)t * CONVDIM + c] = silu_f(acc);
  } else if (tid < 160) {
    int hh = tid - 128;
    float raw = zx[(size_t)t * DPROJ + 4224 + hh] + dtb[hh];
    float sp = raw > 20.f ? raw : log1pf(expf(raw));
    dtsp[t * 32 + hh] = sp;
    dag[t * 32 + hh] = expf(-expf(alog[hh]) * sp);
  }
}

__global__ void k_prefix(const float* __restrict__ dag, float* __restrict__ pref,
                         float* __restrict__ dacum) {
  int gi = blockIdx.x * 256 + threadIdx.x;  // 64*32
  int c = gi >> 5, hh = gi & 31;
  float P = 1.f;
  for (int s_ = 0; s_ < CLEN; ++s_) {
    int t = c * CLEN + s_;
    P *= dag[t * 32 + hh];
    pref[t * 32 + hh] = P;
  }
  dacum[gi] = P;
}

// ---------------------------------------------------------------- chunked scan
__global__ __launch_bounds__(256) void k_scan_local(
    const float* __restrict__ xbc, const float* __restrict__ dtsp,
    const float* __restrict__ dag, float* __restrict__ yb, float* __restrict__ Sloc)
{
  int c = blockIdx.x, hh = blockIdx.y;
  int tid = threadIdx.x;
  int p = tid >> 2, ng = tid & 3, n0 = ng << 4;
  float st[16];
#pragma unroll
  for (int j = 0; j < 16; ++j) st[j] = 0.f;
  for (int s_ = 0; s_ < CLEN; ++s_) {
    int t = c * CLEN + s_;
    float dA = dag[t * 32 + hh];
    float coef = dtsp[t * 32 + hh] * xbc[(size_t)t * CONVDIM + hh * 64 + p];
    const f32x4* B4 = (const f32x4*)&xbc[(size_t)t * CONVDIM + 2048 + n0];
    const f32x4* C4 = (const f32x4*)&xbc[(size_t)t * CONVDIM + 2112 + n0];
    float y = 0.f;
#pragma unroll
    for (int q = 0; q < 4; ++q) {
      f32x4 b = B4[q], cc = C4[q];
#pragma unroll
      for (int e = 0; e < 4; ++e) {
        int j = q * 4 + e;
        st[j] = dA * st[j] + coef * b[e];
        y += st[j] * cc[e];
      }
    }
    y += __shfl_xor(y, 1);
    y += __shfl_xor(y, 2);
    if (ng == 0) yb[(size_t)t * DINNER + hh * 64 + p] = y;
  }
  float* Sp = Sloc + ((size_t)(c * 32 + hh) * 64 + p) * 64 + n0;
#pragma unroll
  for (int q = 0; q < 4; ++q)
    *(f32x4*)(Sp + q * 4) = (f32x4){ st[q*4], st[q*4+1], st[q*4+2], st[q*4+3] };
}

__global__ void k_chain(const float* __restrict__ Sloc, const float* __restrict__ dacum,
                        float* __restrict__ Sin) {
  int e = blockIdx.x * 256 + threadIdx.x;  // 131072
  int hh = e >> 12;
  float S = 0.f;
  for (int c = 0; c < NCHUNK; ++c) {
    Sin[(size_t)c * 131072 + e] = S;
    S = dacum[c * 32 + hh] * S + Sloc[(size_t)c * 131072 + e];
  }
}

__global__ __launch_bounds__(256) void k_scan_fix(
    const float* __restrict__ xbc, const float* __restrict__ pref,
    const float* __restrict__ Sin, const float* __restrict__ Dp,
    float* __restrict__ yb)
{
  __shared__ float Sl[64 * 68];
  int c = blockIdx.x, hh = blockIdx.y;
  int tid = threadIdx.x;
  for (int i = 0; i < 16; ++i) {
    int e = i * 256 + tid;
    Sl[(e >> 6) * 68 + (e & 63)] = Sin[(size_t)(c * 32 + hh) * 4096 + e];
  }
  __syncthreads();
  int p = tid >> 2, ng = tid & 3, n0 = ng << 4;
  float Dh = Dp[hh];
  for (int s_ = 0; s_ < CLEN; ++s_) {
    int t = c * CLEN + s_;
    const f32x4* C4 = (const f32x4*)&xbc[(size_t)t * CONVDIM + 2112 + n0];
    float yc = 0.f;
#pragma unroll
    for (int q = 0; q < 4; ++q) {
      f32x4 cc = C4[q];
#pragma unroll
      for (int e = 0; e < 4; ++e) yc += Sl[p * 68 + n0 + q * 4 + e] * cc[e];
    }
    yc += __shfl_xor(yc, 1);
    yc += __shfl_xor(yc, 2);
    if (ng == 0) {
      size_t oy = (size_t)t * DINNER + hh * 64 + p;
      yb[oy] = yb[oy] + pref[t * 32 + hh] * yc + Dh * xbc[(size_t)t * CONVDIM + hh * 64 + p];
    }
  }
}

__global__ void k_gated_rms(const float* __restrict__ yb, const float* __restrict__ zx,
                            const float* __restrict__ gw, u16* __restrict__ out) {
  int t = blockIdx.x, tid = threadIdx.x;
  float v[8], ss = 0.f;
#pragma unroll
  for (int i = 0; i < 8; ++i) {
    int j = tid + i * 256;
    float z = zx[(size_t)t * DPROJ + j];
    float vv = yb[(size_t)t * DINNER + j] * silu_f(z);
    v[i] = vv; ss += vv * vv;
  }
#pragma unroll
  for (int o = 32; o; o >>= 1) ss += __shfl_down(ss, o);
  __shared__ float sb[4];
  if ((tid & 63) == 0) sb[tid >> 6] = ss;
  __syncthreads();
  ss = sb[0] + sb[1] + sb[2] + sb[3];
  float rstd = rsqrtf(ss * (1.f / 2048.f) + 1e-5f);
#pragma unroll
  for (int i = 0; i < 8; ++i) {
    int j = tid + i * 256;
    out[(size_t)t * DINNER + j] = f2bf(v[i] * rstd * gw[j]);
  }
}

__global__ void k_glu(const float* __restrict__ fc1, u16* __restrict__ out) {
  int gi = blockIdx.x * 256 + threadIdx.x;  // 1024*4096
  int t = gi >> 12, j = gi & 4095;
  float y = fc1[(size_t)t * 8192 + j];
  float g = fc1[(size_t)t * 8192 + 4096 + j];
  out[gi] = f2bf(y * silu_f(g));
}

// ---------------------------------------------------------------- loss
__global__ void k_loss_final(const float* __restrict__ lsepart,
                             const float* __restrict__ logits,
                             const int* __restrict__ tgt, float* __restrict__ part) {
  int t = blockIdx.x, tid = threadIdx.x;
  float m = -1e30f, s = 0.f;
  for (int nb = tid; nb < 393; nb += 256) {
    f32x2 v = ((const f32x2*)lsepart)[(size_t)t * 393 + nb];
    float M = fmaxf(m, v[0]);
    s = s * expf(m - M) + v[1] * expf(v[0] - M);
    m = M;
  }
#pragma unroll
  for (int o = 32; o; o >>= 1) {
    float m2 = __shfl_down(m, o), s2 = __shfl_down(s, o);
    float M = fmaxf(m, m2);
    s = s * expf(m - M) + s2 * expf(m2 - M);
    m = M;
  }
  __shared__ float ms[4], ssh[4];
  if ((tid & 63) == 0) { ms[tid >> 6] = m; ssh[tid >> 6] = s; }
  __syncthreads();
  if (tid == 0) {
    float M = ms[0], S = ssh[0];
    for (int w = 1; w < 4; ++w) {
      float M2 = fmaxf(M, ms[w]);
      S = S * expf(M - M2) + ssh[w] * expf(ms[w] - M2);
      M = M2;
    }
    part[t] = (M + logf(S)) - logits[(size_t)t * VOCAB + tgt[t]];
  }
}

__global__ void k_loss_mean(const float* __restrict__ part, float* __restrict__ out) {
  int tid = threadIdx.x;
  float s = 0.f;
  for (int j = tid; j < 1024; j += 256) s += part[j];
#pragma unroll
  for (int o = 32; o; o >>= 1) s += __shfl_down(s, o);
  __shared__ float sb[4];
  if ((tid & 63) == 0) sb[tid >> 6] = s;
  __syncthreads();
  if (tid == 0) out[0] = (sb[0] + sb[1] + sb[2] + sb[3]) * (1.f / 1024.f);
}

// ---------------------------------------------------------------- launch
extern "C" void kernel_launch(void* const* d_in, const int* in_sizes, int n_in,
                              void* d_out, int out_size, void* d_ws, size_t ws_size,
                              hipStream_t stream)
{
  const int*   idx       = (const int*)d_in[0];
  const int*   tgt       = (const int*)d_in[1];
  const float* E         = (const float*)d_in[2];
  const float* norm_w    = (const float*)d_in[3];
  const float* norm2_w   = (const float*)d_in[4];
  const float* in_proj_w = (const float*)d_in[5];
  const float* conv_w    = (const float*)d_in[6];
  const float* conv_b    = (const float*)d_in[7];
  const float* dt_bias   = (const float*)d_in[8];
  const float* A_log     = (const float*)d_in[9];
  const float* Dp        = (const float*)d_in[10];
  const float* gnorm_w   = (const float*)d_in[11];
  const float* out_proj_w= (const float*)d_in[12];
  const float* fc1_w     = (const float*)d_in[13];
  const float* fc2_w     = (const float*)d_in[14];
  const float* norm_f_w  = (const float*)d_in[15];
  float* logits = (float*)d_out;
  (void)in_sizes; (void)n_in; (void)out_size; (void)ws_size;

  char* W = (char*)d_ws;
  size_t off = 0;
  auto A8 = [&](size_t bytes) { void* p = W + off; off = (off + bytes + 255) & ~(size_t)255; return p; };
  float* hbuf   = (float*)A8((size_t)1024 * 1024 * 4);
  u16*   xnormb = (u16*)  A8((size_t)1024 * 1024 * 2);
  u16*   gatedb = (u16*)  A8((size_t)1024 * 2048 * 2);
  u16*   glub   = (u16*)  A8((size_t)1024 * 4096 * 2);
  float* dtsp   = (float*)A8((size_t)1024 * 32 * 4);
  float* dag    = (float*)A8((size_t)1024 * 32 * 4);
  float* pref   = (float*)A8((size_t)1024 * 32 * 4);
  float* dacum  = (float*)A8((size_t)2048 * 4);
  float* lpart  = (float*)A8((size_t)1024 * 4);
  float* lsebuf = (float*)A8((size_t)1024 * 393 * 2 * 4);
  u16*   wip    = (u16*)  A8((size_t)2 * 4352 * 1024 * 2);
  u16*   wop    = (u16*)  A8((size_t)2 * 1024 * 2048 * 2);
  u16*   wfc1   = (u16*)  A8((size_t)2 * 8192 * 1024 * 2);
  u16*   wfc2   = (u16*)  A8((size_t)2 * 1024 * 4096 * 2);
  // shared span: layer temporaries; Ebf aliases it after layers are done
  char*  span   = (char*)A8((size_t)117964800);
  float* big0   = (float*)(span);                          // 32 MB  (1024x8192)
  float* xbc    = (float*)(span + 33554432);               // 8.5 MB
  float* yb     = (float*)(span + 33554432 + 8912896);     // 8 MB
  float* Sloc   = (float*)(span + 33554432 + 8912896 + 8388608);  // 32 MB
  float* Sin    = (float*)((char*)Sloc + 33554432);        // 32 MB
  float* part   = Sloc;                                    // splitK slices alias
  u16*   Ebf    = (u16*)span;                              // 103 MB alias

  dim3 b256(256);

  k_cvt8_pad<<<dim3((4352*1024/8 + 255)/256), b256, 0, stream>>>(
      in_proj_w, wip, 4352*1024/8, 4256*1024/8);
  k_cvt8_pad<<<dim3((4352*1024/8 + 255)/256), b256, 0, stream>>>(
      in_proj_w + (size_t)4256*1024, wip + (size_t)4352*1024, 4352*1024/8, 4256*1024/8);
  k_cvt8<<<dim3(2*1024*2048/8/256), b256, 0, stream>>>(out_proj_w, wop, 2*1024*2048/8);
  k_cvt8<<<dim3(2*8192*1024/8/256), b256, 0, stream>>>(fc1_w, wfc1, 2*8192*1024/8);
  k_cvt8<<<dim3(2*1024*4096/8/256), b256, 0, stream>>>(fc2_w, wfc2, 2*1024*4096/8);

  k_ln_embed<<<1024, b256, 0, stream>>>(idx, E, norm_w, hbuf, xnormb);

  const float* nw_next[2] = { norm_w + 1024, norm_f_w };
  for (int L = 0; L < 2; ++L) {
    gemm_bf16<<<dim3(8, 34, 1), b256, 0, stream>>>(
        xnormb, wip + (size_t)L * 4352 * 1024, big0, DPROJ, 1024, 1024, nullptr);
    k_convdt<<<dim3(9, 1024), b256, 0, stream>>>(
        big0, conv_w + L * CONVDIM * 4, conv_b + L * CONVDIM,
        dt_bias + L * 32, A_log + L * 32, xbc, dtsp, dag);
    k_prefix<<<8, b256, 0, stream>>>(dag, pref, dacum);
    k_scan_local<<<dim3(64, 32), b256, 0, stream>>>(xbc, dtsp, dag, yb, Sloc);
    k_chain<<<512, b256, 0, stream>>>(Sloc, dacum, Sin);
    k_scan_fix<<<dim3(64, 32), b256, 0, stream>>>(xbc, pref, Sin, Dp + L * 32, yb);
    k_gated_rms<<<1024, b256, 0, stream>>>(yb, big0, gnorm_w + L * 2048, gatedb);
    gemm_bf16<<<dim3(8, 8, 2), b256, 0, stream>>>(
        gatedb, wop + (size_t)L * 1024 * 2048, part, 1024, 2048, 1024, nullptr);
    k_red_ln<<<1024, b256, 0, stream>>>(part, 2, hbuf, norm2_w + L * 1024, xnormb);
    gemm_bf16<<<dim3(8, 64, 1), b256, 0, stream>>>(
        xnormb, wfc1 + (size_t)L * 8192 * 1024, big0, 8192, 1024, 1024, nullptr);
    k_glu<<<16384, b256, 0, stream>>>(big0, glub);
    gemm_bf16<<<dim3(8, 8, 4), b256, 0, stream>>>(
        glub, wfc2 + (size_t)L * 1024 * 4096, part, 1024, 4096, 1024, nullptr);
    k_red_ln<<<1024, b256, 0, stream>>>(part, 4, hbuf, nw_next[L], xnormb);
  }

  k_cvt8_pad<<<dim3((VOCABP*1024/8 + 255)/256), b256, 0, stream>>>(
      E, Ebf, VOCABP*1024/8, VOCAB*1024/8);
  gemm_bf16<<<dim3(8, 393, 1), b256, 0, stream>>>(
      xnormb, Ebf, logits, VOCAB, 1024, 1024, lsebuf);
  k_loss_final<<<1024, b256, 0, stream>>>(lsebuf, logits, tgt, lpart);
  k_loss_mean<<<1, b256, 0, stream>>>(lpart, logits + (size_t)1024 * VOCAB);
}

// Round 4
// 899.659 us; speedup vs baseline: 2.4167x; 1.0318x over previous
//
#include <hip/hip_runtime.h>
#include <cmath>

#define DMODEL  1024
#define DINNER  2048
#define NHEADS  32
#define CONVDIM 2176
#define DPROJ   4256
#define VOCAB   50257
#define NBLK_V  400            // LM-head n-blocks (padded: 400*128 = 51200 rows)
#define VOCABP  (NBLK_V * 128)
#define CLEN    16
#define NCHUNK  64

typedef float f32x4 __attribute__((ext_vector_type(4)));
typedef float f32x2 __attribute__((ext_vector_type(2)));
typedef unsigned short u16;
typedef u16 u16x4 __attribute__((ext_vector_type(4)));
typedef u16 u16x8 __attribute__((ext_vector_type(8)));
typedef __bf16 bf16x8 __attribute__((ext_vector_type(8)));

__device__ __forceinline__ u16 f2bf(float f) {
  unsigned u = __builtin_bit_cast(unsigned, f);
  u += 0x7FFFu + ((u >> 16) & 1u);
  return (u16)(u >> 16);
}
__device__ __forceinline__ float silu_f(float x) { return x / (1.f + expf(-x)); }

__device__ __forceinline__ void gload16(const u16* g, u16* l) {
  __builtin_amdgcn_global_load_lds(
      (const __attribute__((address_space(1))) void*)g,
      (__attribute__((address_space(3))) void*)l,
      16, 0, 0);
}

// ---------------------------------------------------------------- bf16 GEMM
// C[m,n] = sum_k A[m,k]*B[n,k]. A: 1024xK bf16. B: NpadxK bf16 (rows padded
// to x128). BK=64, 128x128 tile, 4 waves.
// T2 swizzle: LDS dest linear (global_load_lds), global source chunk
// pre-permuted by (l&7)^(l>>3); reads use chunk (kk*4+kg)^(row&7).
// swz=1 (LM head): 1-D grid 8*nblk, XCD-bijective so each n-tile lives on
// exactly one XCD's L2 and is reused by its 8 m-blocks.
__global__ __launch_bounds__(256) void gemm_bf16(
    const u16* __restrict__ A, const u16* __restrict__ B,
    float* __restrict__ C, int N, int K, int kslice,
    float* __restrict__ lsepart, int swz, int nblk)
{
  __shared__ alignas(128) u16 As[128 * 64];
  __shared__ alignas(128) u16 Bs[128 * 64];
  const int tid = threadIdx.x;
  int m0, n0;
  if (swz) {
    int bid = blockIdx.x;
    m0 = ((bid >> 3) & 7) << 7;
    n0 = ((bid & 7) + ((bid >> 6) << 3)) << 7;
  } else {
    m0 = blockIdx.x << 7;
    n0 = blockIdx.y << 7;
  }
  const int lane = tid & 63, wid = tid >> 6;
  const int wm = (wid >> 1) << 6, wn = (wid & 1) << 6;
  const int lr = lane & 15, kg = lane >> 4;

  // staging: issue i, wave w, lane l -> LDS row i*32+w*8+(l>>3), phys chunk l&7
  // source chunk = phys ^ (row&7) = (l&7)^(l>>3)
  const int srow = wid * 8 + (lane >> 3);
  const int scol = ((lane & 7) ^ (lane >> 3)) << 3;
  const u16* gA = A + (size_t)(m0 + srow) * K + scol;
  const u16* gB = B + (size_t)(n0 + srow) * K + scol;

  f32x4 acc[4][4];
#pragma unroll
  for (int i = 0; i < 4; ++i)
#pragma unroll
    for (int j = 0; j < 4; ++j) acc[i][j] = (f32x4){0.f, 0.f, 0.f, 0.f};

  const int kb = blockIdx.z * kslice;
  const int ke = kb + kslice;
  for (int k0 = kb; k0 < ke; k0 += 64) {
#pragma unroll
    for (int i = 0; i < 4; ++i) {
      gload16(gA + k0 + (size_t)i * 32 * K, As + i * 2048 + wid * 512);
      gload16(gB + k0 + (size_t)i * 32 * K, Bs + i * 2048 + wid * 512);
    }
    __syncthreads();
#pragma unroll
    for (int kk = 0; kk < 2; ++kk) {
      bf16x8 af[4], bfr[4];
      const int cx = ((kk * 4 + kg) ^ (lr & 7)) << 3;
#pragma unroll
      for (int f = 0; f < 4; ++f) {
        af[f]  = *(const bf16x8*)&As[(wm + f * 16 + lr) * 64 + cx];
        bfr[f] = *(const bf16x8*)&Bs[(wn + f * 16 + lr) * 64 + cx];
      }
#pragma unroll
      for (int i = 0; i < 4; ++i)
#pragma unroll
        for (int j = 0; j < 4; ++j)
          acc[i][j] = __builtin_amdgcn_mfma_f32_16x16x32_bf16(af[i], bfr[j], acc[i][j], 0, 0, 0);
    }
    __syncthreads();
  }

  const int mr = (lane >> 4) << 2;
  const int nc = lane & 15;
  float* Cw = C + (gridDim.z > 1 ? (size_t)blockIdx.z * 1024 * N : 0);
#pragma unroll
  for (int i = 0; i < 4; ++i)
#pragma unroll
    for (int j = 0; j < 4; ++j) {
      int n = n0 + wn + j * 16 + nc;
      if (n < N) {
#pragma unroll
        for (int e = 0; e < 4; ++e)
          Cw[(size_t)(m0 + wm + i * 16 + mr + e) * N + n] = acc[i][j][e];
      }
    }

  if (lsepart) {
    float* Ls = (float*)As;  // [128 rows][2 halves][2]
#pragma unroll
    for (int i = 0; i < 4; ++i)
#pragma unroll
      for (int e = 0; e < 4; ++e) {
        float pm = -1e30f;
#pragma unroll
        for (int j = 0; j < 4; ++j) {
          int n = n0 + wn + j * 16 + nc;
          if (n < N) pm = fmaxf(pm, acc[i][j][e]);
        }
        float ps = 0.f;
#pragma unroll
        for (int j = 0; j < 4; ++j) {
          int n = n0 + wn + j * 16 + nc;
          if (n < N) ps += expf(acc[i][j][e] - pm);
        }
#pragma unroll
        for (int o = 1; o < 16; o <<= 1) {
          float pm2 = __shfl_xor(pm, o), ps2 = __shfl_xor(ps, o);
          float M = fmaxf(pm, pm2);
          ps = ps * expf(pm - M) + ps2 * expf(pm2 - M);
          pm = M;
        }
        if (nc == 0) {
          int row = wm + i * 16 + mr + e;
          Ls[row * 4 + (wid & 1) * 2] = pm;
          Ls[row * 4 + (wid & 1) * 2 + 1] = ps;
        }
      }
    __syncthreads();
    if (tid < 128) {
      float pa = Ls[tid * 4], sa = Ls[tid * 4 + 1];
      float pb = Ls[tid * 4 + 2], sb = Ls[tid * 4 + 3];
      float M = fmaxf(pa, pb);
      float S = sa * expf(pa - M) + sb * expf(pb - M);
      ((f32x2*)lsepart)[(size_t)(m0 + tid) * nblk + (n0 >> 7)] = (f32x2){M, S};
    }
  }
}

// ---------------------------------------------------------------- conversions
__global__ void k_cvt8(const float* __restrict__ src, u16* __restrict__ dst, int n8) {
  int i = blockIdx.x * 256 + threadIdx.x;
  if (i >= n8) return;
  f32x4 a = ((const f32x4*)src)[i * 2];
  f32x4 b = ((const f32x4*)src)[i * 2 + 1];
  u16x8 o = { f2bf(a[0]), f2bf(a[1]), f2bf(a[2]), f2bf(a[3]),
              f2bf(b[0]), f2bf(b[1]), f2bf(b[2]), f2bf(b[3]) };
  ((u16x8*)dst)[i] = o;
}

__global__ void k_cvt8_pad(const float* __restrict__ src, u16* __restrict__ dst,
                           int n8, int srcN8) {
  int i = blockIdx.x * 256 + threadIdx.x;
  if (i >= n8) return;
  u16x8 o;
  if (i < srcN8) {
    f32x4 a = ((const f32x4*)src)[i * 2];
    f32x4 b = ((const f32x4*)src)[i * 2 + 1];
    o = (u16x8){ f2bf(a[0]), f2bf(a[1]), f2bf(a[2]), f2bf(a[3]),
                 f2bf(b[0]), f2bf(b[1]), f2bf(b[2]), f2bf(b[3]) };
  } else {
    o = (u16x8){0, 0, 0, 0, 0, 0, 0, 0};
  }
  ((u16x8*)dst)[i] = o;
}

// ---------------------------------------------------------------- fused LN
__device__ __forceinline__ void ln_write(f32x4 v, const float* __restrict__ w,
                                         u16* __restrict__ out, int t, int tid) {
  float s = v[0] + v[1] + v[2] + v[3];
  float sq = v[0]*v[0] + v[1]*v[1] + v[2]*v[2] + v[3]*v[3];
#pragma unroll
  for (int o = 32; o; o >>= 1) { s += __shfl_down(s, o); sq += __shfl_down(sq, o); }
  __shared__ float sb[4], qb[4];
  if ((tid & 63) == 0) { sb[tid >> 6] = s; qb[tid >> 6] = sq; }
  __syncthreads();
  s = sb[0] + sb[1] + sb[2] + sb[3];
  sq = qb[0] + qb[1] + qb[2] + qb[3];
  float mu = s * (1.f / 1024.f);
  float rstd = rsqrtf(sq * (1.f / 1024.f) - mu * mu + 1e-5f);
  u16x4 o;
#pragma unroll
  for (int e = 0; e < 4; ++e) o[e] = f2bf((v[e] - mu) * rstd * w[tid * 4 + e]);
  ((u16x4*)out)[t * 256 + tid] = o;
}

__global__ void k_ln_embed(const int* __restrict__ idx, const float* __restrict__ E,
                           const float* __restrict__ w, float* __restrict__ hbuf,
                           u16* __restrict__ out) {
  int t = blockIdx.x, tid = threadIdx.x;
  f32x4 v = ((const f32x4*)(E + (size_t)idx[t] * DMODEL))[tid];
  ((f32x4*)hbuf)[t * 256 + tid] = v;
  ln_write(v, w, out, t, tid);
}

__global__ void k_red_ln(const float* __restrict__ part, int S,
                         float* __restrict__ hbuf, const float* __restrict__ w,
                         u16* __restrict__ out) {
  int t = blockIdx.x, tid = threadIdx.x;
  f32x4 v = ((const f32x4*)hbuf)[t * 256 + tid];
  for (int k = 0; k < S; ++k)
    v += ((const f32x4*)part)[(size_t)k * 262144 + t * 256 + tid];
  ((f32x4*)hbuf)[t * 256 + tid] = v;
  ln_write(v, w, out, t, tid);
}

// ---------------------------------------------------------------- conv + dt
__global__ void k_convdt(const float* __restrict__ zx, const float* __restrict__ cw,
                         const float* __restrict__ cb, const float* __restrict__ dtb,
                         const float* __restrict__ alog, float* __restrict__ xbc,
                         float* __restrict__ dtsp, float* __restrict__ dag) {
  int t = blockIdx.y, x = blockIdx.x, tid = threadIdx.x;
  if (x < 8 || tid < 128) {
    int c = x * 256 + tid;
    float acc = cb[c];
#pragma unroll
    for (int k = 0; k < 4; ++k) {
      int tt = t + k - 3;
      if (tt >= 0) acc += zx[(size_t)tt * DPROJ + 2048 + c] * cw[c * 4 + k];
    }
    xbc[(size_t)t * CONVDIM + c] = silu_f(acc);
  } else if (tid < 160) {
    int hh = tid - 128;
    float raw = zx[(size_t)t * DPROJ + 4224 + hh] + dtb[hh];
    float sp = raw > 20.f ? raw : log1pf(expf(raw));
    dtsp[t * 32 + hh] = sp;
    dag[t * 32 + hh] = expf(-expf(alog[hh]) * sp);
  }
}

__global__ void k_prefix(const float* __restrict__ dag, float* __restrict__ pref,
                         float* __restrict__ dacum) {
  int gi = blockIdx.x * 256 + threadIdx.x;  // 64*32
  int c = gi >> 5, hh = gi & 31;
  float P = 1.f;
  for (int s_ = 0; s_ < CLEN; ++s_) {
    int t = c * CLEN + s_;
    P *= dag[t * 32 + hh];
    pref[t * 32 + hh] = P;
  }
  dacum[gi] = P;
}

// ---------------------------------------------------------------- chunked scan
__global__ __launch_bounds__(256) void k_scan_local(
    const float* __restrict__ xbc, const float* __restrict__ dtsp,
    const float* __restrict__ dag, float* __restrict__ yb, float* __restrict__ Sloc)
{
  int c = blockIdx.x, hh = blockIdx.y;
  int tid = threadIdx.x;
  int p = tid >> 2, ng = tid & 3, n0 = ng << 4;
  float st[16];
#pragma unroll
  for (int j = 0; j < 16; ++j) st[j] = 0.f;
  for (int s_ = 0; s_ < CLEN; ++s_) {
    int t = c * CLEN + s_;
    float dA = dag[t * 32 + hh];
    float coef = dtsp[t * 32 + hh] * xbc[(size_t)t * CONVDIM + hh * 64 + p];
    const f32x4* B4 = (const f32x4*)&xbc[(size_t)t * CONVDIM + 2048 + n0];
    const f32x4* C4 = (const f32x4*)&xbc[(size_t)t * CONVDIM + 2112 + n0];
    float y = 0.f;
#pragma unroll
    for (int q = 0; q < 4; ++q) {
      f32x4 b = B4[q], cc = C4[q];
#pragma unroll
      for (int e = 0; e < 4; ++e) {
        int j = q * 4 + e;
        st[j] = dA * st[j] + coef * b[e];
        y += st[j] * cc[e];
      }
    }
    y += __shfl_xor(y, 1);
    y += __shfl_xor(y, 2);
    if (ng == 0) yb[(size_t)t * DINNER + hh * 64 + p] = y;
  }
  float* Sp = Sloc + ((size_t)(c * 32 + hh) * 64 + p) * 64 + n0;
#pragma unroll
  for (int q = 0; q < 4; ++q)
    *(f32x4*)(Sp + q * 4) = (f32x4){ st[q*4], st[q*4+1], st[q*4+2], st[q*4+3] };
}

__global__ void k_chain(const float* __restrict__ Sloc, const float* __restrict__ dacum,
                        float* __restrict__ Sin) {
  int e = blockIdx.x * 256 + threadIdx.x;  // 131072
  int hh = e >> 12;
  float S = 0.f;
  for (int c = 0; c < NCHUNK; ++c) {
    Sin[(size_t)c * 131072 + e] = S;
    S = dacum[c * 32 + hh] * S + Sloc[(size_t)c * 131072 + e];
  }
}

__global__ __launch_bounds__(256) void k_scan_fix(
    const float* __restrict__ xbc, const float* __restrict__ pref,
    const float* __restrict__ Sin, const float* __restrict__ Dp,
    float* __restrict__ yb)
{
  __shared__ float Sl[64 * 68];
  int c = blockIdx.x, hh = blockIdx.y;
  int tid = threadIdx.x;
  for (int i = 0; i < 16; ++i) {
    int e = i * 256 + tid;
    Sl[(e >> 6) * 68 + (e & 63)] = Sin[(size_t)(c * 32 + hh) * 4096 + e];
  }
  __syncthreads();
  int p = tid >> 2, ng = tid & 3, n0 = ng << 4;
  float Dh = Dp[hh];
  for (int s_ = 0; s_ < CLEN; ++s_) {
    int t = c * CLEN + s_;
    const f32x4* C4 = (const f32x4*)&xbc[(size_t)t * CONVDIM + 2112 + n0];
    float yc = 0.f;
#pragma unroll
    for (int q = 0; q < 4; ++q) {
      f32x4 cc = C4[q];
#pragma unroll
      for (int e = 0; e < 4; ++e) yc += Sl[p * 68 + n0 + q * 4 + e] * cc[e];
    }
    yc += __shfl_xor(yc, 1);
    yc += __shfl_xor(yc, 2);
    if (ng == 0) {
      size_t oy = (size_t)t * DINNER + hh * 64 + p;
      yb[oy] = yb[oy] + pref[t * 32 + hh] * yc + Dh * xbc[(size_t)t * CONVDIM + hh * 64 + p];
    }
  }
}

__global__ void k_gated_rms(const float* __restrict__ yb, const float* __restrict__ zx,
                            const float* __restrict__ gw, u16* __restrict__ out) {
  int t = blockIdx.x, tid = threadIdx.x;
  float v[8], ss = 0.f;
#pragma unroll
  for (int i = 0; i < 8; ++i) {
    int j = tid + i * 256;
    float z = zx[(size_t)t * DPROJ + j];
    float vv = yb[(size_t)t * DINNER + j] * silu_f(z);
    v[i] = vv; ss += vv * vv;
  }
#pragma unroll
  for (int o = 32; o; o >>= 1) ss += __shfl_down(ss, o);
  __shared__ float sb[4];
  if ((tid & 63) == 0) sb[tid >> 6] = ss;
  __syncthreads();
  ss = sb[0] + sb[1] + sb[2] + sb[3];
  float rstd = rsqrtf(ss * (1.f / 2048.f) + 1e-5f);
#pragma unroll
  for (int i = 0; i < 8; ++i) {
    int j = tid + i * 256;
    out[(size_t)t * DINNER + j] = f2bf(v[i] * rstd * gw[j]);
  }
}

__global__ void k_glu(const float* __restrict__ fc1, u16* __restrict__ out) {
  int gi = blockIdx.x * 256 + threadIdx.x;  // 1024*4096
  int t = gi >> 12, j = gi & 4095;
  float y = fc1[(size_t)t * 8192 + j];
  float g = fc1[(size_t)t * 8192 + 4096 + j];
  out[gi] = f2bf(y * silu_f(g));
}

// ---------------------------------------------------------------- loss
__global__ void k_loss_final(const float* __restrict__ lsepart,
                             const float* __restrict__ logits,
                             const int* __restrict__ tgt, float* __restrict__ part) {
  int t = blockIdx.x, tid = threadIdx.x;
  float m = -1e30f, s = 0.f;
  for (int nb = tid; nb < NBLK_V; nb += 256) {
    f32x2 v = ((const f32x2*)lsepart)[(size_t)t * NBLK_V + nb];
    float M = fmaxf(m, v[0]);
    s = s * expf(m - M) + v[1] * expf(v[0] - M);
    m = M;
  }
#pragma unroll
  for (int o = 32; o; o >>= 1) {
    float m2 = __shfl_down(m, o), s2 = __shfl_down(s, o);
    float M = fmaxf(m, m2);
    s = s * expf(m - M) + s2 * expf(m2 - M);
    m = M;
  }
  __shared__ float ms[4], ssh[4];
  if ((tid & 63) == 0) { ms[tid >> 6] = m; ssh[tid >> 6] = s; }
  __syncthreads();
  if (tid == 0) {
    float M = ms[0], S = ssh[0];
    for (int w = 1; w < 4; ++w) {
      float M2 = fmaxf(M, ms[w]);
      S = S * expf(M - M2) + ssh[w] * expf(ms[w] - M2);
      M = M2;
    }
    part[t] = (M + logf(S)) - logits[(size_t)t * VOCAB + tgt[t]];
  }
}

__global__ void k_loss_mean(const float* __restrict__ part, float* __restrict__ out) {
  int tid = threadIdx.x;
  float s = 0.f;
  for (int j = tid; j < 1024; j += 256) s += part[j];
#pragma unroll
  for (int o = 32; o; o >>= 1) s += __shfl_down(s, o);
  __shared__ float sb[4];
  if ((tid & 63) == 0) sb[tid >> 6] = s;
  __syncthreads();
  if (tid == 0) out[0] = (sb[0] + sb[1] + sb[2] + sb[3]) * (1.f / 1024.f);
}

// ---------------------------------------------------------------- launch
extern "C" void kernel_launch(void* const* d_in, const int* in_sizes, int n_in,
                              void* d_out, int out_size, void* d_ws, size_t ws_size,
                              hipStream_t stream)
{
  const int*   idx       = (const int*)d_in[0];
  const int*   tgt       = (const int*)d_in[1];
  const float* E         = (const float*)d_in[2];
  const float* norm_w    = (const float*)d_in[3];
  const float* norm2_w   = (const float*)d_in[4];
  const float* in_proj_w = (const float*)d_in[5];
  const float* conv_w    = (const float*)d_in[6];
  const float* conv_b    = (const float*)d_in[7];
  const float* dt_bias   = (const float*)d_in[8];
  const float* A_log     = (const float*)d_in[9];
  const float* Dp        = (const float*)d_in[10];
  const float* gnorm_w   = (const float*)d_in[11];
  const float* out_proj_w= (const float*)d_in[12];
  const float* fc1_w     = (const float*)d_in[13];
  const float* fc2_w     = (const float*)d_in[14];
  const float* norm_f_w  = (const float*)d_in[15];
  float* logits = (float*)d_out;
  (void)in_sizes; (void)n_in; (void)out_size; (void)ws_size;

  char* W = (char*)d_ws;
  size_t off = 0;
  auto A8 = [&](size_t bytes) { void* p = W + off; off = (off + bytes + 255) & ~(size_t)255; return p; };
  float* hbuf   = (float*)A8((size_t)1024 * 1024 * 4);
  u16*   xnormb = (u16*)  A8((size_t)1024 * 1024 * 2);
  u16*   gatedb = (u16*)  A8((size_t)1024 * 2048 * 2);
  u16*   glub   = (u16*)  A8((size_t)1024 * 4096 * 2);
  float* dtsp   = (float*)A8((size_t)1024 * 32 * 4);
  float* dag    = (float*)A8((size_t)1024 * 32 * 4);
  float* pref   = (float*)A8((size_t)1024 * 32 * 4);
  float* dacum  = (float*)A8((size_t)2048 * 4);
  float* lpart  = (float*)A8((size_t)1024 * 4);
  float* lsebuf = (float*)A8((size_t)1024 * NBLK_V * 2 * 4);
  u16*   wip    = (u16*)  A8((size_t)2 * 4352 * 1024 * 2);
  u16*   wop    = (u16*)  A8((size_t)2 * 1024 * 2048 * 2);
  u16*   wfc1   = (u16*)  A8((size_t)2 * 8192 * 1024 * 2);
  u16*   wfc2   = (u16*)  A8((size_t)2 * 1024 * 4096 * 2);
  // shared span: layer temporaries; Ebf aliases it after layers are done
  char*  span   = (char*)A8((size_t)117964800);
  float* big0   = (float*)(span);                          // 32 MB  (1024x8192)
  float* xbc    = (float*)(span + 33554432);               // 8.5 MB
  float* yb     = (float*)(span + 33554432 + 8912896);     // 8 MB
  float* Sloc   = (float*)(span + 33554432 + 8912896 + 8388608);  // 32 MB
  float* Sin    = (float*)((char*)Sloc + 33554432);        // 32 MB
  float* part   = Sloc;                                    // splitK slices alias
  u16*   Ebf    = (u16*)span;                              // 100 MB alias (51200x1024)

  dim3 b256(256);

  k_cvt8_pad<<<dim3((4352*1024/8 + 255)/256), b256, 0, stream>>>(
      in_proj_w, wip, 4352*1024/8, 4256*1024/8);
  k_cvt8_pad<<<dim3((4352*1024/8 + 255)/256), b256, 0, stream>>>(
      in_proj_w + (size_t)4256*1024, wip + (size_t)4352*1024, 4352*1024/8, 4256*1024/8);
  k_cvt8<<<dim3(2*1024*2048/8/256), b256, 0, stream>>>(out_proj_w, wop, 2*1024*2048/8);
  k_cvt8<<<dim3(2*8192*1024/8/256), b256, 0, stream>>>(fc1_w, wfc1, 2*8192*1024/8);
  k_cvt8<<<dim3(2*1024*4096/8/256), b256, 0, stream>>>(fc2_w, wfc2, 2*1024*4096/8);

  k_ln_embed<<<1024, b256, 0, stream>>>(idx, E, norm_w, hbuf, xnormb);

  const float* nw_next[2] = { norm_w + 1024, norm_f_w };
  for (int L = 0; L < 2; ++L) {
    gemm_bf16<<<dim3(8, 34, 1), b256, 0, stream>>>(
        xnormb, wip + (size_t)L * 4352 * 1024, big0, DPROJ, 1024, 1024, nullptr, 0, 34);
    k_convdt<<<dim3(9, 1024), b256, 0, stream>>>(
        big0, conv_w + L * CONVDIM * 4, conv_b + L * CONVDIM,
        dt_bias + L * 32, A_log + L * 32, xbc, dtsp, dag);
    k_prefix<<<8, b256, 0, stream>>>(dag, pref, dacum);
    k_scan_local<<<dim3(64, 32), b256, 0, stream>>>(xbc, dtsp, dag, yb, Sloc);
    k_chain<<<512, b256, 0, stream>>>(Sloc, dacum, Sin);
    k_scan_fix<<<dim3(64, 32), b256, 0, stream>>>(xbc, pref, Sin, Dp + L * 32, yb);
    k_gated_rms<<<1024, b256, 0, stream>>>(yb, big0, gnorm_w + L * 2048, gatedb);
    gemm_bf16<<<dim3(8, 8, 2), b256, 0, stream>>>(
        gatedb, wop + (size_t)L * 1024 * 2048, part, 1024, 2048, 1024, nullptr, 0, 8);
    k_red_ln<<<1024, b256, 0, stream>>>(part, 2, hbuf, norm2_w + L * 1024, xnormb);
    gemm_bf16<<<dim3(8, 64, 1), b256, 0, stream>>>(
        xnormb, wfc1 + (size_t)L * 8192 * 1024, big0, 8192, 1024, 1024, nullptr, 0, 64);
    k_glu<<<16384, b256, 0, stream>>>(big0, glub);
    gemm_bf16<<<dim3(8, 8, 4), b256, 0, stream>>>(
        glub, wfc2 + (size_t)L * 1024 * 4096, part, 1024, 4096, 1024, nullptr, 0, 8);
    k_red_ln<<<1024, b256, 0, stream>>>(part, 4, hbuf, nw_next[L], xnormb);
  }

  k_cvt8_pad<<<dim3((VOCABP*1024/8 + 255)/256), b256, 0, stream>>>(
      E, Ebf, VOCABP*1024/8, VOCAB*1024/8);
  gemm_bf16<<<dim3(8 * NBLK_V, 1, 1), b256, 0, stream>>>(
      xnormb, Ebf, logits, VOCAB, 1024, 1024, lsebuf, 1, NBLK_V);
  k_loss_final<<<1024, b256, 0, stream>>>(lsebuf, logits, tgt, lpart);
  k_loss_mean<<<1, b256, 0, stream>>>(lpart, logits + (size_t)1024 * VOCAB);
}

// Round 5
// 837.231 us; speedup vs baseline: 2.5969x; 1.0746x over previous
//
#include <hip/hip_runtime.h>
#include <cmath>

#define DMODEL  1024
#define DINNER  2048
#define NHEADS  32
#define CONVDIM 2176
#define DPROJ   4256
#define VOCAB   50257
#define NBLK_V  400            // LM-head n-blocks (padded: 400*128 = 51200 rows)
#define VOCABP  (NBLK_V * 128)
#define CLEN    16
#define NCHUNK  64

typedef float f32x4 __attribute__((ext_vector_type(4)));
typedef float f32x2 __attribute__((ext_vector_type(2)));
typedef unsigned short u16;
typedef u16 u16x4 __attribute__((ext_vector_type(4)));
typedef u16 u16x8 __attribute__((ext_vector_type(8)));
typedef __bf16 bf16x8 __attribute__((ext_vector_type(8)));

__device__ __forceinline__ u16 f2bf(float f) {
  unsigned u = __builtin_bit_cast(unsigned, f);
  u += 0x7FFFu + ((u >> 16) & 1u);
  return (u16)(u >> 16);
}
__device__ __forceinline__ float silu_f(float x) { return x / (1.f + expf(-x)); }

__device__ __forceinline__ void gload16(const u16* g, u16* l) {
  __builtin_amdgcn_global_load_lds(
      (const __attribute__((address_space(1))) void*)g,
      (__attribute__((address_space(3))) void*)l,
      16, 0, 0);
}

// ---------------------------------------------------------------- bf16 GEMM
// C[m,n] = sum_k A[m,k]*B[n,k]. A: 1024xK bf16. B: NpadxK bf16 (rows padded
// to x128). BK=64, 128x128 tile, 4 waves, double-buffered LDS with counted
// pipeline (T3 minimum 2-phase): STAGE(next) issued before compute(cur),
// one vmcnt(0)+s_barrier per K-step.
// T2 swizzle: LDS linear, global source chunk pre-permuted by (l&7)^(l>>3);
// reads use chunk (kk*4+kg)^(row&7). Bank conflicts = 0 (R4 measured).
// swz=1 (LM head): 1-D grid 8*nblk, XCD-bijective (FETCH=E once, R4).
// lsepart: per-(row, n-block) online-softmax partials (max-then-sum form).
// glu_out: fc1 GLU fusion — B rows interleaved y0,g0,y1,g1,...; epilogue
// emits bf16 y*silu(g), no f32 C write.
__global__ __launch_bounds__(256) void gemm_bf16(
    const u16* __restrict__ A, const u16* __restrict__ B,
    float* __restrict__ C, int N, int K, int kslice,
    float* __restrict__ lsepart, int swz, int nblk,
    u16* __restrict__ glu_out)
{
  __shared__ alignas(128) u16 As[2][128 * 64];
  __shared__ alignas(128) u16 Bs[2][128 * 64];
  const int tid = threadIdx.x;
  int m0, n0;
  if (swz) {
    int bid = blockIdx.x;
    m0 = ((bid >> 3) & 7) << 7;
    n0 = ((bid & 7) + ((bid >> 6) << 3)) << 7;
  } else {
    m0 = blockIdx.x << 7;
    n0 = blockIdx.y << 7;
  }
  const int lane = tid & 63, wid = tid >> 6;
  const int wm = (wid >> 1) << 6, wn = (wid & 1) << 6;
  const int lr = lane & 15, kg = lane >> 4;

  // staging: issue i, wave w, lane l -> LDS row i*32+w*8+(l>>3), phys chunk l&7
  // source chunk = phys ^ (row&7) = (l&7)^(l>>3)
  const int srow = wid * 8 + (lane >> 3);
  const int scol = ((lane & 7) ^ (lane >> 3)) << 3;
  const u16* gA = A + (size_t)(m0 + srow) * K + scol;
  const u16* gB = B + (size_t)(n0 + srow) * K + scol;

  f32x4 acc[4][4];
#pragma unroll
  for (int i = 0; i < 4; ++i)
#pragma unroll
    for (int j = 0; j < 4; ++j) acc[i][j] = (f32x4){0.f, 0.f, 0.f, 0.f};

  const int kb = blockIdx.z * kslice;
  const int nt = kslice >> 6;

  auto stage = [&](int buf, int kk) {
#pragma unroll
    for (int i = 0; i < 4; ++i) {
      gload16(gA + kk + (size_t)i * 32 * K, &As[buf][i * 2048 + wid * 512]);
      gload16(gB + kk + (size_t)i * 32 * K, &Bs[buf][i * 2048 + wid * 512]);
    }
  };

  stage(0, kb);
  asm volatile("s_waitcnt vmcnt(0)" ::: "memory");
  __builtin_amdgcn_s_barrier();

  int cur = 0;
  for (int t = 0; t < nt; ++t) {
    if (t + 1 < nt) stage(cur ^ 1, kb + (t + 1) * 64);
#pragma unroll
    for (int kk = 0; kk < 2; ++kk) {
      bf16x8 af[4], bfr[4];
      const int cx = ((kk * 4 + kg) ^ (lr & 7)) << 3;
#pragma unroll
      for (int f = 0; f < 4; ++f) {
        af[f]  = *(const bf16x8*)&As[cur][(wm + f * 16 + lr) * 64 + cx];
        bfr[f] = *(const bf16x8*)&Bs[cur][(wn + f * 16 + lr) * 64 + cx];
      }
#pragma unroll
      for (int i = 0; i < 4; ++i)
#pragma unroll
        for (int j = 0; j < 4; ++j)
          acc[i][j] = __builtin_amdgcn_mfma_f32_16x16x32_bf16(af[i], bfr[j], acc[i][j], 0, 0, 0);
    }
    asm volatile("s_waitcnt vmcnt(0)" ::: "memory");
    __builtin_amdgcn_s_barrier();
    cur ^= 1;
  }

  const int mr = (lane >> 4) << 2;
  const int nc = lane & 15;

  if (glu_out) {
    // interleaved cols: even n -> y[n/2], odd n -> g[n/2]
#pragma unroll
    for (int i = 0; i < 4; ++i)
#pragma unroll
      for (int j = 0; j < 4; ++j)
#pragma unroll
        for (int e = 0; e < 4; ++e) {
          float v = acc[i][j][e];
          float p = __shfl_xor(v, 1);
          if (!(nc & 1)) {
            int q = (n0 + wn + j * 16 + nc) >> 1;
            int row = m0 + wm + i * 16 + mr + e;
            glu_out[(size_t)row * 4096 + q] = f2bf(v * silu_f(p));
          }
        }
    return;
  }

  float* Cw = C + (gridDim.z > 1 ? (size_t)blockIdx.z * 1024 * N : 0);
#pragma unroll
  for (int i = 0; i < 4; ++i)
#pragma unroll
    for (int j = 0; j < 4; ++j) {
      int n = n0 + wn + j * 16 + nc;
      if (n < N) {
#pragma unroll
        for (int e = 0; e < 4; ++e)
          Cw[(size_t)(m0 + wm + i * 16 + mr + e) * N + n] = acc[i][j][e];
      }
    }

  if (lsepart) {
    float* Ls = (float*)As;  // [128 rows][2 halves][2]
#pragma unroll
    for (int i = 0; i < 4; ++i)
#pragma unroll
      for (int e = 0; e < 4; ++e) {
        float pm = -1e30f;
#pragma unroll
        for (int j = 0; j < 4; ++j) {
          int n = n0 + wn + j * 16 + nc;
          if (n < N) pm = fmaxf(pm, acc[i][j][e]);
        }
#pragma unroll
        for (int o = 1; o < 16; o <<= 1) pm = fmaxf(pm, __shfl_xor(pm, o));
        float ps = 0.f;
#pragma unroll
        for (int j = 0; j < 4; ++j) {
          int n = n0 + wn + j * 16 + nc;
          if (n < N) ps += expf(acc[i][j][e] - pm);
        }
#pragma unroll
        for (int o = 1; o < 16; o <<= 1) ps += __shfl_xor(ps, o);
        if (nc == 0) {
          int row = wm + i * 16 + mr + e;
          Ls[row * 4 + (wid & 1) * 2] = pm;
          Ls[row * 4 + (wid & 1) * 2 + 1] = ps;
        }
      }
    __syncthreads();
    if (tid < 128) {
      float pa = Ls[tid * 4], sa = Ls[tid * 4 + 1];
      float pb = Ls[tid * 4 + 2], sb = Ls[tid * 4 + 3];
      float M = fmaxf(pa, pb);
      float S = sa * expf(pa - M) + sb * expf(pb - M);
      ((f32x2*)lsepart)[(size_t)(m0 + tid) * nblk + (n0 >> 7)] = (f32x2){M, S};
    }
  }
}

// ---------------------------------------------------------------- conversions
__global__ void k_cvt8(const float* __restrict__ src, u16* __restrict__ dst, int n8) {
  int i = blockIdx.x * 256 + threadIdx.x;
  if (i >= n8) return;
  f32x4 a = ((const f32x4*)src)[i * 2];
  f32x4 b = ((const f32x4*)src)[i * 2 + 1];
  u16x8 o = { f2bf(a[0]), f2bf(a[1]), f2bf(a[2]), f2bf(a[3]),
              f2bf(b[0]), f2bf(b[1]), f2bf(b[2]), f2bf(b[3]) };
  ((u16x8*)dst)[i] = o;
}

__global__ void k_cvt8_pad(const float* __restrict__ src, u16* __restrict__ dst,
                           int n8, int srcN8) {
  int i = blockIdx.x * 256 + threadIdx.x;
  if (i >= n8) return;
  u16x8 o;
  if (i < srcN8) {
    f32x4 a = ((const f32x4*)src)[i * 2];
    f32x4 b = ((const f32x4*)src)[i * 2 + 1];
    o = (u16x8){ f2bf(a[0]), f2bf(a[1]), f2bf(a[2]), f2bf(a[3]),
                 f2bf(b[0]), f2bf(b[1]), f2bf(b[2]), f2bf(b[3]) };
  } else {
    o = (u16x8){0, 0, 0, 0, 0, 0, 0, 0};
  }
  ((u16x8*)dst)[i] = o;
}

// fc1 weights with y/g row interleave: src layer rows [0,4096)=y, [4096,8192)=g
// dst row 2r = y_r, 2r+1 = g_r (per layer)
__global__ void k_cvt_fc1(const float* __restrict__ src, u16* __restrict__ dst, int n8) {
  int i = blockIdx.x * 256 + threadIdx.x;
  if (i >= n8) return;  // n8 = 2*8192*128
  f32x4 a = ((const f32x4*)src)[i * 2];
  f32x4 b = ((const f32x4*)src)[i * 2 + 1];
  u16x8 o = { f2bf(a[0]), f2bf(a[1]), f2bf(a[2]), f2bf(a[3]),
              f2bf(b[0]), f2bf(b[1]), f2bf(b[2]), f2bf(b[3]) };
  int R = i >> 7, col8 = i & 127;
  int layer = R >> 13, r = R & 8191;
  int dstr = (r < 4096) ? (r << 1) : (((r - 4096) << 1) | 1);
  ((u16x8*)dst)[((size_t)(layer << 13) + dstr) * 128 + col8] = o;
}

// ---------------------------------------------------------------- fused LN
__device__ __forceinline__ void ln_write(f32x4 v, const float* __restrict__ w,
                                         u16* __restrict__ out, int t, int tid) {
  float s = v[0] + v[1] + v[2] + v[3];
  float sq = v[0]*v[0] + v[1]*v[1] + v[2]*v[2] + v[3]*v[3];
#pragma unroll
  for (int o = 32; o; o >>= 1) { s += __shfl_down(s, o); sq += __shfl_down(sq, o); }
  __shared__ float sb[4], qb[4];
  if ((tid & 63) == 0) { sb[tid >> 6] = s; qb[tid >> 6] = sq; }
  __syncthreads();
  s = sb[0] + sb[1] + sb[2] + sb[3];
  sq = qb[0] + qb[1] + qb[2] + qb[3];
  float mu = s * (1.f / 1024.f);
  float rstd = rsqrtf(sq * (1.f / 1024.f) - mu * mu + 1e-5f);
  u16x4 o;
#pragma unroll
  for (int e = 0; e < 4; ++e) o[e] = f2bf((v[e] - mu) * rstd * w[tid * 4 + e]);
  ((u16x4*)out)[t * 256 + tid] = o;
}

__global__ void k_ln_embed(const int* __restrict__ idx, const float* __restrict__ E,
                           const float* __restrict__ w, float* __restrict__ hbuf,
                           u16* __restrict__ out) {
  int t = blockIdx.x, tid = threadIdx.x;
  f32x4 v = ((const f32x4*)(E + (size_t)idx[t] * DMODEL))[tid];
  ((f32x4*)hbuf)[t * 256 + tid] = v;
  ln_write(v, w, out, t, tid);
}

__global__ void k_red_ln(const float* __restrict__ part, int S,
                         float* __restrict__ hbuf, const float* __restrict__ w,
                         u16* __restrict__ out) {
  int t = blockIdx.x, tid = threadIdx.x;
  f32x4 v = ((const f32x4*)hbuf)[t * 256 + tid];
  for (int k = 0; k < S; ++k)
    v += ((const f32x4*)part)[(size_t)k * 262144 + t * 256 + tid];
  ((f32x4*)hbuf)[t * 256 + tid] = v;
  ln_write(v, w, out, t, tid);
}

// ---------------------------------------------------------------- conv + dt
__global__ void k_convdt(const float* __restrict__ zx, const float* __restrict__ cw,
                         const float* __restrict__ cb, const float* __restrict__ dtb,
                         const float* __restrict__ alog, float* __restrict__ xbc,
                         float* __restrict__ dtsp, float* __restrict__ dag) {
  int t = blockIdx.y, x = blockIdx.x, tid = threadIdx.x;
  if (x < 8 || tid < 128) {
    int c = x * 256 + tid;
    float acc = cb[c];
#pragma unroll
    for (int k = 0; k < 4; ++k) {
      int tt = t + k - 3;
      if (tt >= 0) acc += zx[(size_t)tt * DPROJ + 2048 + c] * cw[c * 4 + k];
    }
    xbc[(size_t)t * CONVDIM + c] = silu_f(acc);
  } else if (tid < 160) {
    int hh = tid - 128;
    float raw = zx[(size_t)t * DPROJ + 4224 + hh] + dtb[hh];
    float sp = raw > 20.f ? raw : log1pf(expf(raw));
    dtsp[t * 32 + hh] = sp;
    dag[t * 32 + hh] = expf(-expf(alog[hh]) * sp);
  }
}

// ---------------------------------------------------------------- chunked scan
// pass A (+ fused prefix): per (chunk, head) local scan from zero state.
__global__ __launch_bounds__(256) void k_scan_local(
    const float* __restrict__ xbc, const float* __restrict__ dtsp,
    const float* __restrict__ dag, float* __restrict__ yb, float* __restrict__ Sloc,
    float* __restrict__ pref, float* __restrict__ dacum)
{
  int c = blockIdx.x, hh = blockIdx.y;
  int tid = threadIdx.x;
  int p = tid >> 2, ng = tid & 3, n0 = ng << 4;
  float st[16];
#pragma unroll
  for (int j = 0; j < 16; ++j) st[j] = 0.f;
  float P = 1.f;
  for (int s_ = 0; s_ < CLEN; ++s_) {
    int t = c * CLEN + s_;
    float dA = dag[t * 32 + hh];
    P *= dA;
    if (tid == 0) pref[t * 32 + hh] = P;
    float coef = dtsp[t * 32 + hh] * xbc[(size_t)t * CONVDIM + hh * 64 + p];
    const f32x4* B4 = (const f32x4*)&xbc[(size_t)t * CONVDIM + 2048 + n0];
    const f32x4* C4 = (const f32x4*)&xbc[(size_t)t * CONVDIM + 2112 + n0];
    float y = 0.f;
#pragma unroll
    for (int q = 0; q < 4; ++q) {
      f32x4 b = B4[q], cc = C4[q];
#pragma unroll
      for (int e = 0; e < 4; ++e) {
        int j = q * 4 + e;
        st[j] = dA * st[j] + coef * b[e];
        y += st[j] * cc[e];
      }
    }
    y += __shfl_xor(y, 1);
    y += __shfl_xor(y, 2);
    if (ng == 0) yb[(size_t)t * DINNER + hh * 64 + p] = y;
  }
  if (tid == 0) dacum[c * 32 + hh] = P;
  float* Sp = Sloc + ((size_t)(c * 32 + hh) * 64 + p) * 64 + n0;
#pragma unroll
  for (int q = 0; q < 4; ++q)
    *(f32x4*)(Sp + q * 4) = (f32x4){ st[q*4], st[q*4+1], st[q*4+2], st[q*4+3] };
}

__global__ void k_chain(const float* __restrict__ Sloc, const float* __restrict__ dacum,
                        float* __restrict__ Sin) {
  int e = blockIdx.x * 256 + threadIdx.x;  // 131072
  int hh = e >> 12;
  float S = 0.f;
  for (int c = 0; c < NCHUNK; ++c) {
    Sin[(size_t)c * 131072 + e] = S;
    S = dacum[c * 32 + hh] * S + Sloc[(size_t)c * 131072 + e];
  }
}

__global__ __launch_bounds__(256) void k_scan_fix(
    const float* __restrict__ xbc, const float* __restrict__ pref,
    const float* __restrict__ Sin, const float* __restrict__ Dp,
    float* __restrict__ yb)
{
  __shared__ float Sl[64 * 68];
  int c = blockIdx.x, hh = blockIdx.y;
  int tid = threadIdx.x;
  for (int i = 0; i < 16; ++i) {
    int e = i * 256 + tid;
    Sl[(e >> 6) * 68 + (e & 63)] = Sin[(size_t)(c * 32 + hh) * 4096 + e];
  }
  __syncthreads();
  int p = tid >> 2, ng = tid & 3, n0 = ng << 4;
  float Dh = Dp[hh];
  for (int s_ = 0; s_ < CLEN; ++s_) {
    int t = c * CLEN + s_;
    const f32x4* C4 = (const f32x4*)&xbc[(size_t)t * CONVDIM + 2112 + n0];
    float yc = 0.f;
#pragma unroll
    for (int q = 0; q < 4; ++q) {
      f32x4 cc = C4[q];
#pragma unroll
      for (int e = 0; e < 4; ++e) yc += Sl[p * 68 + n0 + q * 4 + e] * cc[e];
    }
    yc += __shfl_xor(yc, 1);
    yc += __shfl_xor(yc, 2);
    if (ng == 0) {
      size_t oy = (size_t)t * DINNER + hh * 64 + p;
      yb[oy] = yb[oy] + pref[t * 32 + hh] * yc + Dh * xbc[(size_t)t * CONVDIM + hh * 64 + p];
    }
  }
}

__global__ void k_gated_rms(const float* __restrict__ yb, const float* __restrict__ zx,
                            const float* __restrict__ gw, u16* __restrict__ out) {
  int t = blockIdx.x, tid = threadIdx.x;
  float v[8], ss = 0.f;
#pragma unroll
  for (int i = 0; i < 8; ++i) {
    int j = tid + i * 256;
    float z = zx[(size_t)t * DPROJ + j];
    float vv = yb[(size_t)t * DINNER + j] * silu_f(z);
    v[i] = vv; ss += vv * vv;
  }
#pragma unroll
  for (int o = 32; o; o >>= 1) ss += __shfl_down(ss, o);
  __shared__ float sb[4];
  if ((tid & 63) == 0) sb[tid >> 6] = ss;
  __syncthreads();
  ss = sb[0] + sb[1] + sb[2] + sb[3];
  float rstd = rsqrtf(ss * (1.f / 2048.f) + 1e-5f);
#pragma unroll
  for (int i = 0; i < 8; ++i) {
    int j = tid + i * 256;
    out[(size_t)t * DINNER + j] = f2bf(v[i] * rstd * gw[j]);
  }
}

// ---------------------------------------------------------------- loss
__global__ void k_loss_final(const float* __restrict__ lsepart,
                             const float* __restrict__ logits,
                             const int* __restrict__ tgt, float* __restrict__ part) {
  int t = blockIdx.x, tid = threadIdx.x;
  float m = -1e30f, s = 0.f;
  for (int nb = tid; nb < NBLK_V; nb += 256) {
    f32x2 v = ((const f32x2*)lsepart)[(size_t)t * NBLK_V + nb];
    float M = fmaxf(m, v[0]);
    s = s * expf(m - M) + v[1] * expf(v[0] - M);
    m = M;
  }
#pragma unroll
  for (int o = 32; o; o >>= 1) {
    float m2 = __shfl_down(m, o), s2 = __shfl_down(s, o);
    float M = fmaxf(m, m2);
    s = s * expf(m - M) + s2 * expf(m2 - M);
    m = M;
  }
  __shared__ float ms[4], ssh[4];
  if ((tid & 63) == 0) { ms[tid >> 6] = m; ssh[tid >> 6] = s; }
  __syncthreads();
  if (tid == 0) {
    float M = ms[0], S = ssh[0];
    for (int w = 1; w < 4; ++w) {
      float M2 = fmaxf(M, ms[w]);
      S = S * expf(M - M2) + ssh[w] * expf(ms[w] - M2);
      M = M2;
    }
    part[t] = (M + logf(S)) - logits[(size_t)t * VOCAB + tgt[t]];
  }
}

__global__ void k_loss_mean(const float* __restrict__ part, float* __restrict__ out) {
  int tid = threadIdx.x;
  float s = 0.f;
  for (int j = tid; j < 1024; j += 256) s += part[j];
#pragma unroll
  for (int o = 32; o; o >>= 1) s += __shfl_down(s, o);
  __shared__ float sb[4];
  if ((tid & 63) == 0) sb[tid >> 6] = s;
  __syncthreads();
  if (tid == 0) out[0] = (sb[0] + sb[1] + sb[2] + sb[3]) * (1.f / 1024.f);
}

// ---------------------------------------------------------------- launch
extern "C" void kernel_launch(void* const* d_in, const int* in_sizes, int n_in,
                              void* d_out, int out_size, void* d_ws, size_t ws_size,
                              hipStream_t stream)
{
  const int*   idx       = (const int*)d_in[0];
  const int*   tgt       = (const int*)d_in[1];
  const float* E         = (const float*)d_in[2];
  const float* norm_w    = (const float*)d_in[3];
  const float* norm2_w   = (const float*)d_in[4];
  const float* in_proj_w = (const float*)d_in[5];
  const float* conv_w    = (const float*)d_in[6];
  const float* conv_b    = (const float*)d_in[7];
  const float* dt_bias   = (const float*)d_in[8];
  const float* A_log     = (const float*)d_in[9];
  const float* Dp        = (const float*)d_in[10];
  const float* gnorm_w   = (const float*)d_in[11];
  const float* out_proj_w= (const float*)d_in[12];
  const float* fc1_w     = (const float*)d_in[13];
  const float* fc2_w     = (const float*)d_in[14];
  const float* norm_f_w  = (const float*)d_in[15];
  float* logits = (float*)d_out;
  (void)in_sizes; (void)n_in; (void)out_size; (void)ws_size;

  char* W = (char*)d_ws;
  size_t off = 0;
  auto A8 = [&](size_t bytes) { void* p = W + off; off = (off + bytes + 255) & ~(size_t)255; return p; };
  float* hbuf   = (float*)A8((size_t)1024 * 1024 * 4);
  u16*   xnormb = (u16*)  A8((size_t)1024 * 1024 * 2);
  u16*   gatedb = (u16*)  A8((size_t)1024 * 2048 * 2);
  u16*   glub   = (u16*)  A8((size_t)1024 * 4096 * 2);
  float* dtsp   = (float*)A8((size_t)1024 * 32 * 4);
  float* dag    = (float*)A8((size_t)1024 * 32 * 4);
  float* pref   = (float*)A8((size_t)1024 * 32 * 4);
  float* dacum  = (float*)A8((size_t)2048 * 4);
  float* lpart  = (float*)A8((size_t)1024 * 4);
  float* lsebuf = (float*)A8((size_t)1024 * NBLK_V * 2 * 4);
  u16*   wip    = (u16*)  A8((size_t)2 * 4352 * 1024 * 2);
  u16*   wop    = (u16*)  A8((size_t)2 * 1024 * 2048 * 2);
  u16*   wfc1   = (u16*)  A8((size_t)2 * 8192 * 1024 * 2);
  u16*   wfc2   = (u16*)  A8((size_t)2 * 1024 * 4096 * 2);
  // shared span: layer temporaries; Ebf aliases it after layers are done
  char*  span   = (char*)A8((size_t)117964800);
  float* big0   = (float*)(span);                          // 17.4 MB (1024x4256)
  float* xbc    = (float*)(span + 33554432);               // 8.5 MB
  float* yb     = (float*)(span + 33554432 + 8912896);     // 8 MB
  float* Sloc   = (float*)(span + 33554432 + 8912896 + 8388608);  // 32 MB
  float* Sin    = (float*)((char*)Sloc + 33554432);        // 32 MB
  float* part   = Sloc;                                    // splitK slices alias
  u16*   Ebf    = (u16*)span;                              // 100 MB alias (51200x1024)

  dim3 b256(256);

  k_cvt8_pad<<<dim3((4352*1024/8 + 255)/256), b256, 0, stream>>>(
      in_proj_w, wip, 4352*1024/8, 4256*1024/8);
  k_cvt8_pad<<<dim3((4352*1024/8 + 255)/256), b256, 0, stream>>>(
      in_proj_w + (size_t)4256*1024, wip + (size_t)4352*1024, 4352*1024/8, 4256*1024/8);
  k_cvt8<<<dim3(2*1024*2048/8/256), b256, 0, stream>>>(out_proj_w, wop, 2*1024*2048/8);
  k_cvt_fc1<<<dim3(2*8192*1024/8/256), b256, 0, stream>>>(fc1_w, wfc1, 2*8192*1024/8);
  k_cvt8<<<dim3(2*1024*4096/8/256), b256, 0, stream>>>(fc2_w, wfc2, 2*1024*4096/8);

  k_ln_embed<<<1024, b256, 0, stream>>>(idx, E, norm_w, hbuf, xnormb);

  const float* nw_next[2] = { norm_w + 1024, norm_f_w };
  for (int L = 0; L < 2; ++L) {
    gemm_bf16<<<dim3(8, 34, 1), b256, 0, stream>>>(
        xnormb, wip + (size_t)L * 4352 * 1024, big0, DPROJ, 1024, 1024,
        nullptr, 0, 34, nullptr);
    k_convdt<<<dim3(9, 1024), b256, 0, stream>>>(
        big0, conv_w + L * CONVDIM * 4, conv_b + L * CONVDIM,
        dt_bias + L * 32, A_log + L * 32, xbc, dtsp, dag);
    k_scan_local<<<dim3(64, 32), b256, 0, stream>>>(xbc, dtsp, dag, yb, Sloc, pref, dacum);
    k_chain<<<512, b256, 0, stream>>>(Sloc, dacum, Sin);
    k_scan_fix<<<dim3(64, 32), b256, 0, stream>>>(xbc, pref, Sin, Dp + L * 32, yb);
    k_gated_rms<<<1024, b256, 0, stream>>>(yb, big0, gnorm_w + L * 2048, gatedb);
    gemm_bf16<<<dim3(8, 8, 2), b256, 0, stream>>>(
        gatedb, wop + (size_t)L * 1024 * 2048, part, 1024, 2048, 1024,
        nullptr, 0, 8, nullptr);
    k_red_ln<<<1024, b256, 0, stream>>>(part, 2, hbuf, norm2_w + L * 1024, xnormb);
    gemm_bf16<<<dim3(8, 64, 1), b256, 0, stream>>>(
        xnormb, wfc1 + (size_t)L * 8192 * 1024, nullptr, 8192, 1024, 1024,
        nullptr, 0, 64, glub);
    gemm_bf16<<<dim3(8, 8, 4), b256, 0, stream>>>(
        glub, wfc2 + (size_t)L * 1024 * 4096, part, 1024, 4096, 1024,
        nullptr, 0, 8, nullptr);
    k_red_ln<<<1024, b256, 0, stream>>>(part, 4, hbuf, nw_next[L], xnormb);
  }

  k_cvt8_pad<<<dim3((VOCABP*1024/8 + 255)/256), b256, 0, stream>>>(
      E, Ebf, VOCABP*1024/8, VOCAB*1024/8);
  gemm_bf16<<<dim3(8 * NBLK_V, 1, 1), b256, 0, stream>>>(
      xnormb, Ebf, logits, VOCAB, 1024, 1024, lsebuf, 1, NBLK_V, nullptr);
  k_loss_final<<<1024, b256, 0, stream>>>(lsebuf, logits, tgt, lpart);
  k_loss_mean<<<1, b256, 0, stream>>>(lpart, logits + (size_t)1024 * VOCAB);
}

// Round 6
// 823.897 us; speedup vs baseline: 2.6389x; 1.0162x over previous
//
#include <hip/hip_runtime.h>
#include <cmath>

#define DMODEL  1024
#define DINNER  2048
#define NHEADS  32
#define CONVDIM 2176
#define DPROJ   4256
#define VOCAB   50257
#define NBLK_V  400            // LM-head n-blocks (padded: 400*128 = 51200 rows)
#define VOCABP  (NBLK_V * 128)
#define CLEN    16
#define NCHUNK  64

typedef float f32x4 __attribute__((ext_vector_type(4)));
typedef float f32x2 __attribute__((ext_vector_type(2)));
typedef unsigned short u16;
typedef u16 u16x4 __attribute__((ext_vector_type(4)));
typedef u16 u16x8 __attribute__((ext_vector_type(8)));
typedef __bf16 bf16x8 __attribute__((ext_vector_type(8)));

__device__ __forceinline__ u16 f2bf(float f) {
  unsigned u = __builtin_bit_cast(unsigned, f);
  u += 0x7FFFu + ((u >> 16) & 1u);
  return (u16)(u >> 16);
}
__device__ __forceinline__ float silu_f(float x) { return x / (1.f + expf(-x)); }

__device__ __forceinline__ void gload16(const u16* g, u16* l) {
  __builtin_amdgcn_global_load_lds(
      (const __attribute__((address_space(1))) void*)g,
      (__attribute__((address_space(3))) void*)l,
      16, 0, 0);
}

// ---------------------------------------------------------------- bf16 GEMM
// C[m,n] = sum_k A[m,k]*B[n,k]. A: 1024xK bf16. B: NpadxK bf16 (rows x128).
// BK=32, 128x128 tile, 4 waves, LDS 48KB = 3-deep pipeline (3 blocks/CU).
// Counted vmcnt(4): tile t+2 stays in flight while computing tile t (T4);
// load-to-use distance = 2 iterations (covers HBM latency).
// Swizzle (64B rows, 4x16B chunks): phys chunk = data chunk ^ ((row>>1)&3).
// Staging keeps LDS linear (global_load_lds): source col pre-permuted
// (l&3)^((l>>3)&3); reads use kg^((lr>>1)&3). 2 lanes/bank max (free).
// swz=1 (LM head): 1-D grid 8*nblk, XCD-bijective (E fetched once, R4).
__global__ __launch_bounds__(256) void gemm_bf16(
    const u16* __restrict__ A, const u16* __restrict__ B,
    float* __restrict__ C, int N, int K, int kslice,
    float* __restrict__ lsepart, int swz, int nblk,
    u16* __restrict__ glu_out)
{
  __shared__ alignas(128) u16 As[3 * 4096];
  __shared__ alignas(128) u16 Bs[3 * 4096];
  const int tid = threadIdx.x;
  int m0, n0;
  if (swz) {
    int bid = blockIdx.x;
    m0 = ((bid >> 3) & 7) << 7;
    n0 = ((bid & 7) + ((bid >> 6) << 3)) << 7;
  } else {
    m0 = blockIdx.x << 7;
    n0 = blockIdx.y << 7;
  }
  const int lane = tid & 63, wid = tid >> 6;
  const int wm = (wid >> 1) << 6, wn = (wid & 1) << 6;
  const int lr = lane & 15, kg = lane >> 4;

  // staging: issue i, wave w, lane l -> LDS row i*64+w*16+(l>>2), phys chunk l&3
  // source chunk = (l&3) ^ ((row>>1)&3) = (l&3) ^ ((l>>3)&3)
  const int srow = wid * 16 + (lane >> 2);
  const int scol = ((lane & 3) ^ ((lane >> 3) & 3)) << 3;
  const u16* gA = A + (size_t)(m0 + srow) * K + scol;
  const u16* gB = B + (size_t)(n0 + srow) * K + scol;

  f32x4 acc[4][4];
#pragma unroll
  for (int i = 0; i < 4; ++i)
#pragma unroll
    for (int j = 0; j < 4; ++j) acc[i][j] = (f32x4){0.f, 0.f, 0.f, 0.f};

  const int kb = blockIdx.z * kslice;
  const int nt = kslice >> 5;

  auto stage = [&](int buf, int t) {
    const int ko = kb + (t << 5);
#pragma unroll
    for (int i = 0; i < 2; ++i) {
      gload16(gA + ko + (size_t)i * 64 * K, &As[buf * 4096 + i * 2048 + wid * 512]);
      gload16(gB + ko + (size_t)i * 64 * K, &Bs[buf * 4096 + i * 2048 + wid * 512]);
    }
  };

  stage(0, 0);
  stage(1, 1);
  int b0 = 0, b1 = 1, b2 = 2;
  const int cxr = ((lr >> 1) & 3);     // read-side swizzle key
  for (int t = 0; t < nt; ++t) {
    if (t == nt - 1) asm volatile("s_waitcnt vmcnt(0)" ::: "memory");
    else             asm volatile("s_waitcnt vmcnt(4)" ::: "memory");
    __builtin_amdgcn_s_barrier();
    if (t + 2 < nt) stage(b2, t + 2);
    bf16x8 af[4], bfr[4];
#pragma unroll
    for (int f = 0; f < 4; ++f) {
      const int po = ((kg ^ cxr) << 3);
      af[f]  = *(const bf16x8*)&As[b0 * 4096 + (wm + f * 16 + lr) * 32 + po];
      bfr[f] = *(const bf16x8*)&Bs[b0 * 4096 + (wn + f * 16 + lr) * 32 + po];
    }
#pragma unroll
    for (int i = 0; i < 4; ++i)
#pragma unroll
      for (int j = 0; j < 4; ++j)
        acc[i][j] = __builtin_amdgcn_mfma_f32_16x16x32_bf16(af[i], bfr[j], acc[i][j], 0, 0, 0);
    int tmp = b0; b0 = b1; b1 = b2; b2 = tmp;
  }

  const int mr = (lane >> 4) << 2;
  const int nc = lane & 15;

  if (glu_out) {
    // interleaved cols: even n -> y[n/2], odd n -> g[n/2]
#pragma unroll
    for (int i = 0; i < 4; ++i)
#pragma unroll
      for (int j = 0; j < 4; ++j)
#pragma unroll
        for (int e = 0; e < 4; ++e) {
          float v = acc[i][j][e];
          float p = __shfl_xor(v, 1);
          if (!(nc & 1)) {
            int q = (n0 + wn + j * 16 + nc) >> 1;
            int row = m0 + wm + i * 16 + mr + e;
            glu_out[(size_t)row * 4096 + q] = f2bf(v * silu_f(p));
          }
        }
    return;
  }

  float* Cw = C + (gridDim.z > 1 ? (size_t)blockIdx.z * 1024 * N : 0);
#pragma unroll
  for (int i = 0; i < 4; ++i)
#pragma unroll
    for (int j = 0; j < 4; ++j) {
      int n = n0 + wn + j * 16 + nc;
      if (n < N) {
#pragma unroll
        for (int e = 0; e < 4; ++e)
          Cw[(size_t)(m0 + wm + i * 16 + mr + e) * N + n] = acc[i][j][e];
      }
    }

  if (lsepart) {
    __syncthreads();           // As reused as scratch; other waves may still read
    float* Ls = (float*)As;    // [128 rows][2 halves][2]
#pragma unroll
    for (int i = 0; i < 4; ++i)
#pragma unroll
      for (int e = 0; e < 4; ++e) {
        float pm = -1e30f;
#pragma unroll
        for (int j = 0; j < 4; ++j) {
          int n = n0 + wn + j * 16 + nc;
          if (n < N) pm = fmaxf(pm, acc[i][j][e]);
        }
#pragma unroll
        for (int o = 1; o < 16; o <<= 1) pm = fmaxf(pm, __shfl_xor(pm, o));
        float ps = 0.f;
#pragma unroll
        for (int j = 0; j < 4; ++j) {
          int n = n0 + wn + j * 16 + nc;
          if (n < N) ps += expf(acc[i][j][e] - pm);
        }
#pragma unroll
        for (int o = 1; o < 16; o <<= 1) ps += __shfl_xor(ps, o);
        if (nc == 0) {
          int row = wm + i * 16 + mr + e;
          Ls[row * 4 + (wid & 1) * 2] = pm;
          Ls[row * 4 + (wid & 1) * 2 + 1] = ps;
        }
      }
    __syncthreads();
    if (tid < 128) {
      float pa = Ls[tid * 4], sa = Ls[tid * 4 + 1];
      float pb = Ls[tid * 4 + 2], sb = Ls[tid * 4 + 3];
      float M = fmaxf(pa, pb);
      float S = sa * expf(pa - M) + sb * expf(pb - M);
      ((f32x2*)lsepart)[(size_t)(m0 + tid) * nblk + (n0 >> 7)] = (f32x2){M, S};
    }
  }
}

// ---------------------------------------------------------------- conversions
__global__ void k_cvt8(const float* __restrict__ src, u16* __restrict__ dst, int n8) {
  int i = blockIdx.x * 256 + threadIdx.x;
  if (i >= n8) return;
  f32x4 a = ((const f32x4*)src)[i * 2];
  f32x4 b = ((const f32x4*)src)[i * 2 + 1];
  u16x8 o = { f2bf(a[0]), f2bf(a[1]), f2bf(a[2]), f2bf(a[3]),
              f2bf(b[0]), f2bf(b[1]), f2bf(b[2]), f2bf(b[3]) };
  ((u16x8*)dst)[i] = o;
}

__global__ void k_cvt8_pad(const float* __restrict__ src, u16* __restrict__ dst,
                           int n8, int srcN8) {
  int i = blockIdx.x * 256 + threadIdx.x;
  if (i >= n8) return;
  u16x8 o;
  if (i < srcN8) {
    f32x4 a = ((const f32x4*)src)[i * 2];
    f32x4 b = ((const f32x4*)src)[i * 2 + 1];
    o = (u16x8){ f2bf(a[0]), f2bf(a[1]), f2bf(a[2]), f2bf(a[3]),
                 f2bf(b[0]), f2bf(b[1]), f2bf(b[2]), f2bf(b[3]) };
  } else {
    o = (u16x8){0, 0, 0, 0, 0, 0, 0, 0};
  }
  ((u16x8*)dst)[i] = o;
}

// fc1 weights with y/g row interleave: src layer rows [0,4096)=y, [4096,8192)=g
__global__ void k_cvt_fc1(const float* __restrict__ src, u16* __restrict__ dst, int n8) {
  int i = blockIdx.x * 256 + threadIdx.x;
  if (i >= n8) return;  // n8 = 2*8192*128
  f32x4 a = ((const f32x4*)src)[i * 2];
  f32x4 b = ((const f32x4*)src)[i * 2 + 1];
  u16x8 o = { f2bf(a[0]), f2bf(a[1]), f2bf(a[2]), f2bf(a[3]),
              f2bf(b[0]), f2bf(b[1]), f2bf(b[2]), f2bf(b[3]) };
  int R = i >> 7, col8 = i & 127;
  int layer = R >> 13, r = R & 8191;
  int dstr = (r < 4096) ? (r << 1) : (((r - 4096) << 1) | 1);
  ((u16x8*)dst)[((size_t)(layer << 13) + dstr) * 128 + col8] = o;
}

// ---------------------------------------------------------------- fused LN
__device__ __forceinline__ void ln_write(f32x4 v, const float* __restrict__ w,
                                         u16* __restrict__ out, int t, int tid) {
  float s = v[0] + v[1] + v[2] + v[3];
  float sq = v[0]*v[0] + v[1]*v[1] + v[2]*v[2] + v[3]*v[3];
#pragma unroll
  for (int o = 32; o; o >>= 1) { s += __shfl_down(s, o); sq += __shfl_down(sq, o); }
  __shared__ float sb[4], qb[4];
  if ((tid & 63) == 0) { sb[tid >> 6] = s; qb[tid >> 6] = sq; }
  __syncthreads();
  s = sb[0] + sb[1] + sb[2] + sb[3];
  sq = qb[0] + qb[1] + qb[2] + qb[3];
  float mu = s * (1.f / 1024.f);
  float rstd = rsqrtf(sq * (1.f / 1024.f) - mu * mu + 1e-5f);
  u16x4 o;
#pragma unroll
  for (int e = 0; e < 4; ++e) o[e] = f2bf((v[e] - mu) * rstd * w[tid * 4 + e]);
  ((u16x4*)out)[t * 256 + tid] = o;
}

__global__ void k_ln_embed(const int* __restrict__ idx, const float* __restrict__ E,
                           const float* __restrict__ w, float* __restrict__ hbuf,
                           u16* __restrict__ out) {
  int t = blockIdx.x, tid = threadIdx.x;
  f32x4 v = ((const f32x4*)(E + (size_t)idx[t] * DMODEL))[tid];
  ((f32x4*)hbuf)[t * 256 + tid] = v;
  ln_write(v, w, out, t, tid);
}

__global__ void k_red_ln(const float* __restrict__ part, int S,
                         float* __restrict__ hbuf, const float* __restrict__ w,
                         u16* __restrict__ out) {
  int t = blockIdx.x, tid = threadIdx.x;
  f32x4 v = ((const f32x4*)hbuf)[t * 256 + tid];
  for (int k = 0; k < S; ++k)
    v += ((const f32x4*)part)[(size_t)k * 262144 + t * 256 + tid];
  ((f32x4*)hbuf)[t * 256 + tid] = v;
  ln_write(v, w, out, t, tid);
}

// ---------------------------------------------------------------- conv + dt
__global__ void k_convdt(const float* __restrict__ zx, const float* __restrict__ cw,
                         const float* __restrict__ cb, const float* __restrict__ dtb,
                         const float* __restrict__ alog, float* __restrict__ xbc,
                         float* __restrict__ dtsp, float* __restrict__ dag) {
  int t = blockIdx.y, x = blockIdx.x, tid = threadIdx.x;
  if (x < 8 || tid < 128) {
    int c = x * 256 + tid;
    float acc = cb[c];
#pragma unroll
    for (int k = 0; k < 4; ++k) {
      int tt = t + k - 3;
      if (tt >= 0) acc += zx[(size_t)tt * DPROJ + 2048 + c] * cw[c * 4 + k];
    }
    xbc[(size_t)t * CONVDIM + c] = silu_f(acc);
  } else if (tid < 160) {
    int hh = tid - 128;
    float raw = zx[(size_t)t * DPROJ + 4224 + hh] + dtb[hh];
    float sp = raw > 20.f ? raw : log1pf(expf(raw));
    dtsp[t * 32 + hh] = sp;
    dag[t * 32 + hh] = expf(-expf(alog[hh]) * sp);
  }
}

// ---------------------------------------------------------------- chunked scan
__global__ __launch_bounds__(256) void k_scan_local(
    const float* __restrict__ xbc, const float* __restrict__ dtsp,
    const float* __restrict__ dag, float* __restrict__ yb, float* __restrict__ Sloc,
    float* __restrict__ pref, float* __restrict__ dacum)
{
  int c = blockIdx.x, hh = blockIdx.y;
  int tid = threadIdx.x;
  int p = tid >> 2, ng = tid & 3, n0 = ng << 4;
  float st[16];
#pragma unroll
  for (int j = 0; j < 16; ++j) st[j] = 0.f;
  float P = 1.f;
  for (int s_ = 0; s_ < CLEN; ++s_) {
    int t = c * CLEN + s_;
    float dA = dag[t * 32 + hh];
    P *= dA;
    if (tid == 0) pref[t * 32 + hh] = P;
    float coef = dtsp[t * 32 + hh] * xbc[(size_t)t * CONVDIM + hh * 64 + p];
    const f32x4* B4 = (const f32x4*)&xbc[(size_t)t * CONVDIM + 2048 + n0];
    const f32x4* C4 = (const f32x4*)&xbc[(size_t)t * CONVDIM + 2112 + n0];
    float y = 0.f;
#pragma unroll
    for (int q = 0; q < 4; ++q) {
      f32x4 b = B4[q], cc = C4[q];
#pragma unroll
      for (int e = 0; e < 4; ++e) {
        int j = q * 4 + e;
        st[j] = dA * st[j] + coef * b[e];
        y += st[j] * cc[e];
      }
    }
    y += __shfl_xor(y, 1);
    y += __shfl_xor(y, 2);
    if (ng == 0) yb[(size_t)t * DINNER + hh * 64 + p] = y;
  }
  if (tid == 0) dacum[c * 32 + hh] = P;
  float* Sp = Sloc + ((size_t)(c * 32 + hh) * 64 + p) * 64 + n0;
#pragma unroll
  for (int q = 0; q < 4; ++q)
    *(f32x4*)(Sp + q * 4) = (f32x4){ st[q*4], st[q*4+1], st[q*4+2], st[q*4+3] };
}

// sequential over 64 chunks; 8-wide load batching to hide latency
__global__ void k_chain(const float* __restrict__ Sloc, const float* __restrict__ dacum,
                        float* __restrict__ Sin) {
  int e = blockIdx.x * 256 + threadIdx.x;  // 131072
  int hh = e >> 12;
  float S = 0.f;
  for (int c = 0; c < NCHUNK; c += 8) {
    float sl[8], dd[8];
#pragma unroll
    for (int j = 0; j < 8; ++j) sl[j] = Sloc[(size_t)(c + j) * 131072 + e];
#pragma unroll
    for (int j = 0; j < 8; ++j) dd[j] = dacum[(c + j) * 32 + hh];
#pragma unroll
    for (int j = 0; j < 8; ++j) {
      Sin[(size_t)(c + j) * 131072 + e] = S;
      S = dd[j] * S + sl[j];
    }
  }
}

__global__ __launch_bounds__(256) void k_scan_fix(
    const float* __restrict__ xbc, const float* __restrict__ pref,
    const float* __restrict__ Sin, const float* __restrict__ Dp,
    float* __restrict__ yb)
{
  __shared__ float Sl[64 * 68];
  int c = blockIdx.x, hh = blockIdx.y;
  int tid = threadIdx.x;
  for (int i = 0; i < 16; ++i) {
    int e = i * 256 + tid;
    Sl[(e >> 6) * 68 + (e & 63)] = Sin[(size_t)(c * 32 + hh) * 4096 + e];
  }
  __syncthreads();
  int p = tid >> 2, ng = tid & 3, n0 = ng << 4;
  float Dh = Dp[hh];
  for (int s_ = 0; s_ < CLEN; ++s_) {
    int t = c * CLEN + s_;
    const f32x4* C4 = (const f32x4*)&xbc[(size_t)t * CONVDIM + 2112 + n0];
    float yc = 0.f;
#pragma unroll
    for (int q = 0; q < 4; ++q) {
      f32x4 cc = C4[q];
#pragma unroll
      for (int e = 0; e < 4; ++e) yc += Sl[p * 68 + n0 + q * 4 + e] * cc[e];
    }
    yc += __shfl_xor(yc, 1);
    yc += __shfl_xor(yc, 2);
    if (ng == 0) {
      size_t oy = (size_t)t * DINNER + hh * 64 + p;
      yb[oy] = yb[oy] + pref[t * 32 + hh] * yc + Dh * xbc[(size_t)t * CONVDIM + hh * 64 + p];
    }
  }
}

__global__ void k_gated_rms(const float* __restrict__ yb, const float* __restrict__ zx,
                            const float* __restrict__ gw, u16* __restrict__ out) {
  int t = blockIdx.x, tid = threadIdx.x;
  float v[8], ss = 0.f;
#pragma unroll
  for (int i = 0; i < 8; ++i) {
    int j = tid + i * 256;
    float z = zx[(size_t)t * DPROJ + j];
    float vv = yb[(size_t)t * DINNER + j] * silu_f(z);
    v[i] = vv; ss += vv * vv;
  }
#pragma unroll
  for (int o = 32; o; o >>= 1) ss += __shfl_down(ss, o);
  __shared__ float sb[4];
  if ((tid & 63) == 0) sb[tid >> 6] = ss;
  __syncthreads();
  ss = sb[0] + sb[1] + sb[2] + sb[3];
  float rstd = rsqrtf(ss * (1.f / 2048.f) + 1e-5f);
#pragma unroll
  for (int i = 0; i < 8; ++i) {
    int j = tid + i * 256;
    out[(size_t)t * DINNER + j] = f2bf(v[i] * rstd * gw[j]);
  }
}

// ---------------------------------------------------------------- loss
__global__ void k_loss_final(const float* __restrict__ lsepart,
                             const float* __restrict__ logits,
                             const int* __restrict__ tgt, float* __restrict__ part) {
  int t = blockIdx.x, tid = threadIdx.x;
  float m = -1e30f, s = 0.f;
  for (int nb = tid; nb < NBLK_V; nb += 256) {
    f32x2 v = ((const f32x2*)lsepart)[(size_t)t * NBLK_V + nb];
    float M = fmaxf(m, v[0]);
    s = s * expf(m - M) + v[1] * expf(v[0] - M);
    m = M;
  }
#pragma unroll
  for (int o = 32; o; o >>= 1) {
    float m2 = __shfl_down(m, o), s2 = __shfl_down(s, o);
    float M = fmaxf(m, m2);
    s = s * expf(m - M) + s2 * expf(m2 - M);
    m = M;
  }
  __shared__ float ms[4], ssh[4];
  if ((tid & 63) == 0) { ms[tid >> 6] = m; ssh[tid >> 6] = s; }
  __syncthreads();
  if (tid == 0) {
    float M = ms[0], S = ssh[0];
    for (int w = 1; w < 4; ++w) {
      float M2 = fmaxf(M, ms[w]);
      S = S * expf(M - M2) + ssh[w] * expf(ms[w] - M2);
      M = M2;
    }
    part[t] = (M + logf(S)) - logits[(size_t)t * VOCAB + tgt[t]];
  }
}

__global__ void k_loss_mean(const float* __restrict__ part, float* __restrict__ out) {
  int tid = threadIdx.x;
  float s = 0.f;
  for (int j = tid; j < 1024; j += 256) s += part[j];
#pragma unroll
  for (int o = 32; o; o >>= 1) s += __shfl_down(s, o);
  __shared__ float sb[4];
  if ((tid & 63) == 0) sb[tid >> 6] = s;
  __syncthreads();
  if (tid == 0) out[0] = (sb[0] + sb[1] + sb[2] + sb[3]) * (1.f / 1024.f);
}

// ---------------------------------------------------------------- launch
extern "C" void kernel_launch(void* const* d_in, const int* in_sizes, int n_in,
                              void* d_out, int out_size, void* d_ws, size_t ws_size,
                              hipStream_t stream)
{
  const int*   idx       = (const int*)d_in[0];
  const int*   tgt       = (const int*)d_in[1];
  const float* E         = (const float*)d_in[2];
  const float* norm_w    = (const float*)d_in[3];
  const float* norm2_w   = (const float*)d_in[4];
  const float* in_proj_w = (const float*)d_in[5];
  const float* conv_w    = (const float*)d_in[6];
  const float* conv_b    = (const float*)d_in[7];
  const float* dt_bias   = (const float*)d_in[8];
  const float* A_log     = (const float*)d_in[9];
  const float* Dp        = (const float*)d_in[10];
  const float* gnorm_w   = (const float*)d_in[11];
  const float* out_proj_w= (const float*)d_in[12];
  const float* fc1_w     = (const float*)d_in[13];
  const float* fc2_w     = (const float*)d_in[14];
  const float* norm_f_w  = (const float*)d_in[15];
  float* logits = (float*)d_out;
  (void)in_sizes; (void)n_in; (void)out_size; (void)ws_size;

  char* W = (char*)d_ws;
  size_t off = 0;
  auto A8 = [&](size_t bytes) { void* p = W + off; off = (off + bytes + 255) & ~(size_t)255; return p; };
  float* hbuf   = (float*)A8((size_t)1024 * 1024 * 4);
  u16*   xnormb = (u16*)  A8((size_t)1024 * 1024 * 2);
  u16*   gatedb = (u16*)  A8((size_t)1024 * 2048 * 2);
  u16*   glub   = (u16*)  A8((size_t)1024 * 4096 * 2);
  float* dtsp   = (float*)A8((size_t)1024 * 32 * 4);
  float* dag    = (float*)A8((size_t)1024 * 32 * 4);
  float* pref   = (float*)A8((size_t)1024 * 32 * 4);
  float* dacum  = (float*)A8((size_t)2048 * 4);
  float* lpart  = (float*)A8((size_t)1024 * 4);
  float* lsebuf = (float*)A8((size_t)1024 * NBLK_V * 2 * 4);
  u16*   wip    = (u16*)  A8((size_t)2 * 4352 * 1024 * 2);
  u16*   wop    = (u16*)  A8((size_t)2 * 1024 * 2048 * 2);
  u16*   wfc1   = (u16*)  A8((size_t)2 * 8192 * 1024 * 2);
  u16*   wfc2   = (u16*)  A8((size_t)2 * 1024 * 4096 * 2);
  // shared span: layer temporaries; Ebf aliases it after layers are done
  char*  span   = (char*)A8((size_t)117964800);
  float* big0   = (float*)(span);                          // 17.4 MB (1024x4256)
  float* xbc    = (float*)(span + 33554432);               // 8.5 MB
  float* yb     = (float*)(span + 33554432 + 8912896);     // 8 MB
  float* Sloc   = (float*)(span + 33554432 + 8912896 + 8388608);  // 32 MB
  float* Sin    = (float*)((char*)Sloc + 33554432);        // 32 MB
  float* part   = Sloc;                                    // splitK slices alias (32MB = 8 slices)
  u16*   Ebf    = (u16*)span;                              // 100 MB alias (51200x1024)

  dim3 b256(256);

  k_cvt8_pad<<<dim3((4352*1024/8 + 255)/256), b256, 0, stream>>>(
      in_proj_w, wip, 4352*1024/8, 4256*1024/8);
  k_cvt8_pad<<<dim3((4352*1024/8 + 255)/256), b256, 0, stream>>>(
      in_proj_w + (size_t)4256*1024, wip + (size_t)4352*1024, 4352*1024/8, 4256*1024/8);
  k_cvt8<<<dim3(2*1024*2048/8/256), b256, 0, stream>>>(out_proj_w, wop, 2*1024*2048/8);
  k_cvt_fc1<<<dim3(2*8192*1024/8/256), b256, 0, stream>>>(fc1_w, wfc1, 2*8192*1024/8);
  k_cvt8<<<dim3(2*1024*4096/8/256), b256, 0, stream>>>(fc2_w, wfc2, 2*1024*4096/8);

  k_ln_embed<<<1024, b256, 0, stream>>>(idx, E, norm_w, hbuf, xnormb);

  const float* nw_next[2] = { norm_w + 1024, norm_f_w };
  for (int L = 0; L < 2; ++L) {
    gemm_bf16<<<dim3(8, 34, 1), b256, 0, stream>>>(
        xnormb, wip + (size_t)L * 4352 * 1024, big0, DPROJ, 1024, 1024,
        nullptr, 0, 34, nullptr);
    k_convdt<<<dim3(9, 1024), b256, 0, stream>>>(
        big0, conv_w + L * CONVDIM * 4, conv_b + L * CONVDIM,
        dt_bias + L * 32, A_log + L * 32, xbc, dtsp, dag);
    k_scan_local<<<dim3(64, 32), b256, 0, stream>>>(xbc, dtsp, dag, yb, Sloc, pref, dacum);
    k_chain<<<512, b256, 0, stream>>>(Sloc, dacum, Sin);
    k_scan_fix<<<dim3(64, 32), b256, 0, stream>>>(xbc, pref, Sin, Dp + L * 32, yb);
    k_gated_rms<<<1024, b256, 0, stream>>>(yb, big0, gnorm_w + L * 2048, gatedb);
    gemm_bf16<<<dim3(8, 8, 4), b256, 0, stream>>>(
        gatedb, wop + (size_t)L * 1024 * 2048, part, 1024, 2048, 512,
        nullptr, 0, 8, nullptr);
    k_red_ln<<<1024, b256, 0, stream>>>(part, 4, hbuf, norm2_w + L * 1024, xnormb);
    gemm_bf16<<<dim3(8, 64, 1), b256, 0, stream>>>(
        xnormb, wfc1 + (size_t)L * 8192 * 1024, nullptr, 8192, 1024, 1024,
        nullptr, 0, 64, glub);
    gemm_bf16<<<dim3(8, 8, 8), b256, 0, stream>>>(
        glub, wfc2 + (size_t)L * 1024 * 4096, part, 1024, 4096, 512,
        nullptr, 0, 8, nullptr);
    k_red_ln<<<1024, b256, 0, stream>>>(part, 8, hbuf, nw_next[L], xnormb);
  }

  k_cvt8_pad<<<dim3((VOCABP*1024/8 + 255)/256), b256, 0, stream>>>(
      E, Ebf, VOCABP*1024/8, VOCAB*1024/8);
  gemm_bf16<<<dim3(8 * NBLK_V, 1, 1), b256, 0, stream>>>(
      xnormb, Ebf, logits, VOCAB, 1024, 1024, lsebuf, 1, NBLK_V, nullptr);
  k_loss_final<<<1024, b256, 0, stream>>>(lsebuf, logits, tgt, lpart);
  k_loss_mean<<<1, b256, 0, stream>>>(lpart, logits + (size_t)1024 * VOCAB);
}

// Round 7
// 785.983 us; speedup vs baseline: 2.7662x; 1.0482x over previous
//
#include <hip/hip_runtime.h>
#include <cmath>

#define DMODEL  1024
#define DINNER  2048
#define NHEADS  32
#define CONVDIM 2176
#define DPROJ   4256
#define VOCAB   50257
#define NBLK_V  400            // LM-head n-blocks (padded: 400*128 = 51200 rows)
#define VOCABP  (NBLK_V * 128)
#define CLEN    32
#define NCHUNK  32

typedef float f32x4 __attribute__((ext_vector_type(4)));
typedef float f32x2 __attribute__((ext_vector_type(2)));
typedef unsigned short u16;
typedef u16 u16x4 __attribute__((ext_vector_type(4)));
typedef u16 u16x8 __attribute__((ext_vector_type(8)));
typedef __bf16 bf16x8 __attribute__((ext_vector_type(8)));

__device__ __forceinline__ u16 f2bf(float f) {
  unsigned u = __builtin_bit_cast(unsigned, f);
  u += 0x7FFFu + ((u >> 16) & 1u);
  return (u16)(u >> 16);
}
__device__ __forceinline__ float silu_f(float x) { return x / (1.f + expf(-x)); }

__device__ __forceinline__ void gload16(const u16* g, u16* l) {
  __builtin_amdgcn_global_load_lds(
      (const __attribute__((address_space(1))) void*)g,
      (__attribute__((address_space(3))) void*)l,
      16, 0, 0);
}

// ---------------------------------------------------------------- 128x128 GEMM
// (4 waves, BK=32, 3-deep, counted vmcnt(4)) — for in_proj / out_proj / fc2.
// Swizzle: 64B rows, phys chunk = data ^ ((row>>1)&3); source pre-permuted.
__global__ __launch_bounds__(256) void gemm_bf16(
    const u16* __restrict__ A, const u16* __restrict__ B,
    float* __restrict__ C, int N, int K, int kslice)
{
  __shared__ alignas(128) u16 As[3 * 4096];
  __shared__ alignas(128) u16 Bs[3 * 4096];
  const int tid = threadIdx.x;
  const int m0 = blockIdx.x << 7;
  const int n0 = blockIdx.y << 7;
  const int lane = tid & 63, wid = tid >> 6;
  const int wm = (wid >> 1) << 6, wn = (wid & 1) << 6;
  const int lr = lane & 15, kg = lane >> 4;

  const int srow = wid * 16 + (lane >> 2);
  const int scol = ((lane & 3) ^ ((lane >> 3) & 3)) << 3;
  const u16* gA = A + (size_t)(m0 + srow) * K + scol;
  const u16* gB = B + (size_t)(n0 + srow) * K + scol;

  f32x4 acc[4][4];
#pragma unroll
  for (int i = 0; i < 4; ++i)
#pragma unroll
    for (int j = 0; j < 4; ++j) acc[i][j] = (f32x4){0.f, 0.f, 0.f, 0.f};

  const int kb = blockIdx.z * kslice;
  const int nt = kslice >> 5;

  auto stage = [&](int buf, int t) {
    const int ko = kb + (t << 5);
#pragma unroll
    for (int i = 0; i < 2; ++i) {
      gload16(gA + ko + (size_t)i * 64 * K, &As[buf * 4096 + i * 2048 + wid * 512]);
      gload16(gB + ko + (size_t)i * 64 * K, &Bs[buf * 4096 + i * 2048 + wid * 512]);
    }
  };

  stage(0, 0);
  stage(1, 1);
  int b0 = 0, b1 = 1, b2 = 2;
  const int cxr = ((lr >> 1) & 3);
  for (int t = 0; t < nt; ++t) {
    if (t == nt - 1) asm volatile("s_waitcnt vmcnt(0)" ::: "memory");
    else             asm volatile("s_waitcnt vmcnt(4)" ::: "memory");
    __builtin_amdgcn_s_barrier();
    if (t + 2 < nt) stage(b2, t + 2);
    bf16x8 af[4], bfr[4];
    const int po = ((kg ^ cxr) << 3);
#pragma unroll
    for (int f = 0; f < 4; ++f) {
      af[f]  = *(const bf16x8*)&As[b0 * 4096 + (wm + f * 16 + lr) * 32 + po];
      bfr[f] = *(const bf16x8*)&Bs[b0 * 4096 + (wn + f * 16 + lr) * 32 + po];
    }
#pragma unroll
    for (int i = 0; i < 4; ++i)
#pragma unroll
      for (int j = 0; j < 4; ++j)
        acc[i][j] = __builtin_amdgcn_mfma_f32_16x16x32_bf16(af[i], bfr[j], acc[i][j], 0, 0, 0);
    int tmp = b0; b0 = b1; b1 = b2; b2 = tmp;
  }

  const int mr = (lane >> 4) << 2;
  const int nc = lane & 15;
  float* Cw = C + (gridDim.z > 1 ? (size_t)blockIdx.z * 1024 * N : 0);
#pragma unroll
  for (int i = 0; i < 4; ++i)
#pragma unroll
    for (int j = 0; j < 4; ++j) {
      int n = n0 + wn + j * 16 + nc;
      if (n < N) {
#pragma unroll
        for (int e = 0; e < 4; ++e)
          Cw[(size_t)(m0 + wm + i * 16 + mr + e) * N + n] = acc[i][j][e];
      }
    }
}

// ---------------------------------------------------------------- 256x128 GEMM
// 8 waves (512 thr), BM=256, BN=128, BK=32, 3-deep LDS (72KB -> 2 blocks/CU,
// 16 waves/CU), counted vmcnt(3) (3 gloads/wave/stage: 2 A + 1 B).
// swz=1: LM head, 1-D grid 4m x 400n XCD-bijective; lsepart partials.
// glu_out: fc1 fusion (interleaved y/g rows).
__global__ __launch_bounds__(512) void gemm256(
    const u16* __restrict__ A, const u16* __restrict__ B,
    float* __restrict__ C, int N, int K,
    float* __restrict__ lsepart, int swz, int nblk,
    u16* __restrict__ glu_out)
{
  __shared__ alignas(128) u16 As[3 * 8192];   // 3 x 256x32
  __shared__ alignas(128) u16 Bs[3 * 4096];   // 3 x 128x32
  const int tid = threadIdx.x;
  int m0, n0;
  if (swz) {
    int bid = blockIdx.x;
    m0 = ((bid >> 3) & 3) << 8;
    n0 = ((bid & 7) + ((bid >> 5) << 3)) << 7;
  } else {
    m0 = blockIdx.x << 8;
    n0 = blockIdx.y << 7;
  }
  const int lane = tid & 63, wid = tid >> 6;       // 8 waves
  const int wm = (wid >> 1) << 6, wn = (wid & 1) << 6;
  const int lr = lane & 15, kg = lane >> 4;

  const int srow = wid * 16 + (lane >> 2);         // 128 rows per issue
  const int scol = ((lane & 3) ^ ((lane >> 3) & 3)) << 3;
  const u16* gA = A + (size_t)(m0 + srow) * K + scol;
  const u16* gB = B + (size_t)(n0 + srow) * K + scol;

  f32x4 acc[4][4];
#pragma unroll
  for (int i = 0; i < 4; ++i)
#pragma unroll
    for (int j = 0; j < 4; ++j) acc[i][j] = (f32x4){0.f, 0.f, 0.f, 0.f};

  const int nt = K >> 5;

  auto stage = [&](int buf, int t) {
    const int ko = t << 5;
    gload16(gA + ko,                     &As[buf * 8192 + wid * 512]);
    gload16(gA + ko + (size_t)128 * K,   &As[buf * 8192 + 4096 + wid * 512]);
    gload16(gB + ko,                     &Bs[buf * 4096 + wid * 512]);
  };

  stage(0, 0);
  stage(1, 1);
  int b0 = 0, b1 = 1, b2 = 2;
  const int cxr = ((lr >> 1) & 3);
  for (int t = 0; t < nt; ++t) {
    if (t == nt - 1) asm volatile("s_waitcnt vmcnt(0)" ::: "memory");
    else             asm volatile("s_waitcnt vmcnt(3)" ::: "memory");
    __builtin_amdgcn_s_barrier();
    if (t + 2 < nt) stage(b2, t + 2);
    bf16x8 af[4], bfr[4];
    const int po = ((kg ^ cxr) << 3);
#pragma unroll
    for (int f = 0; f < 4; ++f) {
      af[f]  = *(const bf16x8*)&As[b0 * 8192 + (wm + f * 16 + lr) * 32 + po];
      bfr[f] = *(const bf16x8*)&Bs[b0 * 4096 + (wn + f * 16 + lr) * 32 + po];
    }
#pragma unroll
    for (int i = 0; i < 4; ++i)
#pragma unroll
      for (int j = 0; j < 4; ++j)
        acc[i][j] = __builtin_amdgcn_mfma_f32_16x16x32_bf16(af[i], bfr[j], acc[i][j], 0, 0, 0);
    int tmp = b0; b0 = b1; b1 = b2; b2 = tmp;
  }

  const int mr = (lane >> 4) << 2;
  const int nc = lane & 15;

  if (glu_out) {
#pragma unroll
    for (int i = 0; i < 4; ++i)
#pragma unroll
      for (int j = 0; j < 4; ++j)
#pragma unroll
        for (int e = 0; e < 4; ++e) {
          float v = acc[i][j][e];
          float p = __shfl_xor(v, 1);
          if (!(nc & 1)) {
            int q = (n0 + wn + j * 16 + nc) >> 1;
            int row = m0 + wm + i * 16 + mr + e;
            glu_out[(size_t)row * 4096 + q] = f2bf(v * silu_f(p));
          }
        }
    return;
  }

#pragma unroll
  for (int i = 0; i < 4; ++i)
#pragma unroll
    for (int j = 0; j < 4; ++j) {
      int n = n0 + wn + j * 16 + nc;
      if (n < N) {
#pragma unroll
        for (int e = 0; e < 4; ++e)
          C[(size_t)(m0 + wm + i * 16 + mr + e) * N + n] = acc[i][j][e];
      }
    }

  if (lsepart) {
    __syncthreads();
    float* Ls = (float*)As;    // [256 rows][2 halves][2] = 4KB
#pragma unroll
    for (int i = 0; i < 4; ++i)
#pragma unroll
      for (int e = 0; e < 4; ++e) {
        float pm = -1e30f;
#pragma unroll
        for (int j = 0; j < 4; ++j) {
          int n = n0 + wn + j * 16 + nc;
          if (n < N) pm = fmaxf(pm, acc[i][j][e]);
        }
#pragma unroll
        for (int o = 1; o < 16; o <<= 1) pm = fmaxf(pm, __shfl_xor(pm, o));
        float ps = 0.f;
#pragma unroll
        for (int j = 0; j < 4; ++j) {
          int n = n0 + wn + j * 16 + nc;
          if (n < N) ps += expf(acc[i][j][e] - pm);
        }
#pragma unroll
        for (int o = 1; o < 16; o <<= 1) ps += __shfl_xor(ps, o);
        if (nc == 0) {
          int row = wm + i * 16 + mr + e;
          Ls[row * 4 + (wid & 1) * 2] = pm;
          Ls[row * 4 + (wid & 1) * 2 + 1] = ps;
        }
      }
    __syncthreads();
    if (tid < 256) {
      float pa = Ls[tid * 4], sa = Ls[tid * 4 + 1];
      float pb = Ls[tid * 4 + 2], sb = Ls[tid * 4 + 3];
      float M = fmaxf(pa, pb);
      float S = sa * expf(pa - M) + sb * expf(pb - M);
      ((f32x2*)lsepart)[(size_t)(m0 + tid) * nblk + (n0 >> 7)] = (f32x2){M, S};
    }
  }
}

// ---------------------------------------------------------------- conversions
__global__ void k_cvt8(const float* __restrict__ src, u16* __restrict__ dst, int n8) {
  int i = blockIdx.x * 256 + threadIdx.x;
  if (i >= n8) return;
  f32x4 a = ((const f32x4*)src)[i * 2];
  f32x4 b = ((const f32x4*)src)[i * 2 + 1];
  u16x8 o = { f2bf(a[0]), f2bf(a[1]), f2bf(a[2]), f2bf(a[3]),
              f2bf(b[0]), f2bf(b[1]), f2bf(b[2]), f2bf(b[3]) };
  ((u16x8*)dst)[i] = o;
}

__global__ void k_cvt8_pad(const float* __restrict__ src, u16* __restrict__ dst,
                           int n8, int srcN8) {
  int i = blockIdx.x * 256 + threadIdx.x;
  if (i >= n8) return;
  u16x8 o;
  if (i < srcN8) {
    f32x4 a = ((const f32x4*)src)[i * 2];
    f32x4 b = ((const f32x4*)src)[i * 2 + 1];
    o = (u16x8){ f2bf(a[0]), f2bf(a[1]), f2bf(a[2]), f2bf(a[3]),
                 f2bf(b[0]), f2bf(b[1]), f2bf(b[2]), f2bf(b[3]) };
  } else {
    o = (u16x8){0, 0, 0, 0, 0, 0, 0, 0};
  }
  ((u16x8*)dst)[i] = o;
}

// fc1 weights with y/g row interleave
__global__ void k_cvt_fc1(const float* __restrict__ src, u16* __restrict__ dst, int n8) {
  int i = blockIdx.x * 256 + threadIdx.x;
  if (i >= n8) return;  // n8 = 2*8192*128
  f32x4 a = ((const f32x4*)src)[i * 2];
  f32x4 b = ((const f32x4*)src)[i * 2 + 1];
  u16x8 o = { f2bf(a[0]), f2bf(a[1]), f2bf(a[2]), f2bf(a[3]),
              f2bf(b[0]), f2bf(b[1]), f2bf(b[2]), f2bf(b[3]) };
  int R = i >> 7, col8 = i & 127;
  int layer = R >> 13, r = R & 8191;
  int dstr = (r < 4096) ? (r << 1) : (((r - 4096) << 1) | 1);
  ((u16x8*)dst)[((size_t)(layer << 13) + dstr) * 128 + col8] = o;
}

// ---------------------------------------------------------------- fused LN
__device__ __forceinline__ void ln_write(f32x4 v, const float* __restrict__ w,
                                         u16* __restrict__ out, int t, int tid) {
  float s = v[0] + v[1] + v[2] + v[3];
  float sq = v[0]*v[0] + v[1]*v[1] + v[2]*v[2] + v[3]*v[3];
#pragma unroll
  for (int o = 32; o; o >>= 1) { s += __shfl_down(s, o); sq += __shfl_down(sq, o); }
  __shared__ float sb[4], qb[4];
  if ((tid & 63) == 0) { sb[tid >> 6] = s; qb[tid >> 6] = sq; }
  __syncthreads();
  s = sb[0] + sb[1] + sb[2] + sb[3];
  sq = qb[0] + qb[1] + qb[2] + qb[3];
  float mu = s * (1.f / 1024.f);
  float rstd = rsqrtf(sq * (1.f / 1024.f) - mu * mu + 1e-5f);
  u16x4 o;
#pragma unroll
  for (int e = 0; e < 4; ++e) o[e] = f2bf((v[e] - mu) * rstd * w[tid * 4 + e]);
  ((u16x4*)out)[t * 256 + tid] = o;
}

__global__ void k_ln_embed(const int* __restrict__ idx, const float* __restrict__ E,
                           const float* __restrict__ w, float* __restrict__ hbuf,
                           u16* __restrict__ out) {
  int t = blockIdx.x, tid = threadIdx.x;
  f32x4 v = ((const f32x4*)(E + (size_t)idx[t] * DMODEL))[tid];
  ((f32x4*)hbuf)[t * 256 + tid] = v;
  ln_write(v, w, out, t, tid);
}

__global__ void k_red_ln(const float* __restrict__ part, int S,
                         float* __restrict__ hbuf, const float* __restrict__ w,
                         u16* __restrict__ out) {
  int t = blockIdx.x, tid = threadIdx.x;
  f32x4 v = ((const f32x4*)hbuf)[t * 256 + tid];
  for (int k = 0; k < S; ++k)
    v += ((const f32x4*)part)[(size_t)k * 262144 + t * 256 + tid];
  ((f32x4*)hbuf)[t * 256 + tid] = v;
  ln_write(v, w, out, t, tid);
}

// ---------------------------------------------------------------- conv + dt
__global__ void k_convdt(const float* __restrict__ zx, const float* __restrict__ cw,
                         const float* __restrict__ cb, const float* __restrict__ dtb,
                         const float* __restrict__ alog, float* __restrict__ xbc,
                         float* __restrict__ dtsp, float* __restrict__ dag) {
  int t = blockIdx.y, x = blockIdx.x, tid = threadIdx.x;
  if (x < 8 || tid < 128) {
    int c = x * 256 + tid;
    float acc = cb[c];
#pragma unroll
    for (int k = 0; k < 4; ++k) {
      int tt = t + k - 3;
      if (tt >= 0) acc += zx[(size_t)tt * DPROJ + 2048 + c] * cw[c * 4 + k];
    }
    xbc[(size_t)t * CONVDIM + c] = silu_f(acc);
  } else if (tid < 160) {
    int hh = tid - 128;
    float raw = zx[(size_t)t * DPROJ + 4224 + hh] + dtb[hh];
    float sp = raw > 20.f ? raw : log1pf(expf(raw));
    dtsp[t * 32 + hh] = sp;
    dag[t * 32 + hh] = expf(-expf(alog[hh]) * sp);
  }
}

// ---------------------------------------------------------------- chunked scan
__global__ __launch_bounds__(256) void k_scan_local(
    const float* __restrict__ xbc, const float* __restrict__ dtsp,
    const float* __restrict__ dag, float* __restrict__ yb, float* __restrict__ Sloc,
    float* __restrict__ pref, float* __restrict__ dacum)
{
  int c = blockIdx.x, hh = blockIdx.y;
  int tid = threadIdx.x;
  int p = tid >> 2, ng = tid & 3, n0 = ng << 4;
  float st[16];
#pragma unroll
  for (int j = 0; j < 16; ++j) st[j] = 0.f;
  float P = 1.f;
  for (int s_ = 0; s_ < CLEN; ++s_) {
    int t = c * CLEN + s_;
    float dA = dag[t * 32 + hh];
    P *= dA;
    if (tid == 0) pref[t * 32 + hh] = P;
    float coef = dtsp[t * 32 + hh] * xbc[(size_t)t * CONVDIM + hh * 64 + p];
    const f32x4* B4 = (const f32x4*)&xbc[(size_t)t * CONVDIM + 2048 + n0];
    const f32x4* C4 = (const f32x4*)&xbc[(size_t)t * CONVDIM + 2112 + n0];
    float y = 0.f;
#pragma unroll
    for (int q = 0; q < 4; ++q) {
      f32x4 b = B4[q], cc = C4[q];
#pragma unroll
      for (int e = 0; e < 4; ++e) {
        int j = q * 4 + e;
        st[j] = dA * st[j] + coef * b[e];
        y += st[j] * cc[e];
      }
    }
    y += __shfl_xor(y, 1);
    y += __shfl_xor(y, 2);
    if (ng == 0) yb[(size_t)t * DINNER + hh * 64 + p] = y;
  }
  if (tid == 0) dacum[c * 32 + hh] = P;
  float* Sp = Sloc + ((size_t)(c * 32 + hh) * 64 + p) * 64 + n0;
#pragma unroll
  for (int q = 0; q < 4; ++q)
    *(f32x4*)(Sp + q * 4) = (f32x4){ st[q*4], st[q*4+1], st[q*4+2], st[q*4+3] };
}

// sequential over chunks; 8-wide load batching to hide latency
__global__ void k_chain(const float* __restrict__ Sloc, const float* __restrict__ dacum,
                        float* __restrict__ Sin) {
  int e = blockIdx.x * 256 + threadIdx.x;  // 131072
  int hh = e >> 12;
  float S = 0.f;
  for (int c = 0; c < NCHUNK; c += 8) {
    float sl[8], dd[8];
#pragma unroll
    for (int j = 0; j < 8; ++j) sl[j] = Sloc[(size_t)(c + j) * 131072 + e];
#pragma unroll
    for (int j = 0; j < 8; ++j) dd[j] = dacum[(c + j) * 32 + hh];
#pragma unroll
    for (int j = 0; j < 8; ++j) {
      Sin[(size_t)(c + j) * 131072 + e] = S;
      S = dd[j] * S + sl[j];
    }
  }
}

__global__ __launch_bounds__(256) void k_scan_fix(
    const float* __restrict__ xbc, const float* __restrict__ pref,
    const float* __restrict__ Sin, const float* __restrict__ Dp,
    float* __restrict__ yb)
{
  __shared__ float Sl[64 * 68];
  int c = blockIdx.x, hh = blockIdx.y;
  int tid = threadIdx.x;
  for (int i = 0; i < 16; ++i) {
    int e = i * 256 + tid;
    Sl[(e >> 6) * 68 + (e & 63)] = Sin[(size_t)(c * 32 + hh) * 4096 + e];
  }
  __syncthreads();
  int p = tid >> 2, ng = tid & 3, n0 = ng << 4;
  float Dh = Dp[hh];
  for (int s_ = 0; s_ < CLEN; ++s_) {
    int t = c * CLEN + s_;
    const f32x4* C4 = (const f32x4*)&xbc[(size_t)t * CONVDIM + 2112 + n0];
    float yc = 0.f;
#pragma unroll
    for (int q = 0; q < 4; ++q) {
      f32x4 cc = C4[q];
#pragma unroll
      for (int e = 0; e < 4; ++e) yc += Sl[p * 68 + n0 + q * 4 + e] * cc[e];
    }
    yc += __shfl_xor(yc, 1);
    yc += __shfl_xor(yc, 2);
    if (ng == 0) {
      size_t oy = (size_t)t * DINNER + hh * 64 + p;
      yb[oy] = yb[oy] + pref[t * 32 + hh] * yc + Dh * xbc[(size_t)t * CONVDIM + hh * 64 + p];
    }
  }
}

__global__ void k_gated_rms(const float* __restrict__ yb, const float* __restrict__ zx,
                            const float* __restrict__ gw, u16* __restrict__ out) {
  int t = blockIdx.x, tid = threadIdx.x;
  float v[8], ss = 0.f;
#pragma unroll
  for (int i = 0; i < 8; ++i) {
    int j = tid + i * 256;
    float z = zx[(size_t)t * DPROJ + j];
    float vv = yb[(size_t)t * DINNER + j] * silu_f(z);
    v[i] = vv; ss += vv * vv;
  }
#pragma unroll
  for (int o = 32; o; o >>= 1) ss += __shfl_down(ss, o);
  __shared__ float sb[4];
  if ((tid & 63) == 0) sb[tid >> 6] = ss;
  __syncthreads();
  ss = sb[0] + sb[1] + sb[2] + sb[3];
  float rstd = rsqrtf(ss * (1.f / 2048.f) + 1e-5f);
#pragma unroll
  for (int i = 0; i < 8; ++i) {
    int j = tid + i * 256;
    out[(size_t)t * DINNER + j] = f2bf(v[i] * rstd * gw[j]);
  }
}

// ---------------------------------------------------------------- loss
__global__ void k_loss_final(const float* __restrict__ lsepart,
                             const float* __restrict__ logits,
                             const int* __restrict__ tgt, float* __restrict__ part) {
  int t = blockIdx.x, tid = threadIdx.x;
  float m = -1e30f, s = 0.f;
  for (int nb = tid; nb < NBLK_V; nb += 256) {
    f32x2 v = ((const f32x2*)lsepart)[(size_t)t * NBLK_V + nb];
    float M = fmaxf(m, v[0]);
    s = s * expf(m - M) + v[1] * expf(v[0] - M);
    m = M;
  }
#pragma unroll
  for (int o = 32; o; o >>= 1) {
    float m2 = __shfl_down(m, o), s2 = __shfl_down(s, o);
    float M = fmaxf(m, m2);
    s = s * expf(m - M) + s2 * expf(m2 - M);
    m = M;
  }
  __shared__ float ms[4], ssh[4];
  if ((tid & 63) == 0) { ms[tid >> 6] = m; ssh[tid >> 6] = s; }
  __syncthreads();
  if (tid == 0) {
    float M = ms[0], S = ssh[0];
    for (int w = 1; w < 4; ++w) {
      float M2 = fmaxf(M, ms[w]);
      S = S * expf(M - M2) + ssh[w] * expf(ms[w] - M2);
      M = M2;
    }
    part[t] = (M + logf(S)) - logits[(size_t)t * VOCAB + tgt[t]];
  }
}

__global__ void k_loss_mean(const float* __restrict__ part, float* __restrict__ out) {
  int tid = threadIdx.x;
  float s = 0.f;
  for (int j = tid; j < 1024; j += 256) s += part[j];
#pragma unroll
  for (int o = 32; o; o >>= 1) s += __shfl_down(s, o);
  __shared__ float sb[4];
  if ((tid & 63) == 0) sb[tid >> 6] = s;
  __syncthreads();
  if (tid == 0) out[0] = (sb[0] + sb[1] + sb[2] + sb[3]) * (1.f / 1024.f);
}

// ---------------------------------------------------------------- launch
extern "C" void kernel_launch(void* const* d_in, const int* in_sizes, int n_in,
                              void* d_out, int out_size, void* d_ws, size_t ws_size,
                              hipStream_t stream)
{
  const int*   idx       = (const int*)d_in[0];
  const int*   tgt       = (const int*)d_in[1];
  const float* E         = (const float*)d_in[2];
  const float* norm_w    = (const float*)d_in[3];
  const float* norm2_w   = (const float*)d_in[4];
  const float* in_proj_w = (const float*)d_in[5];
  const float* conv_w    = (const float*)d_in[6];
  const float* conv_b    = (const float*)d_in[7];
  const float* dt_bias   = (const float*)d_in[8];
  const float* A_log     = (const float*)d_in[9];
  const float* Dp        = (const float*)d_in[10];
  const float* gnorm_w   = (const float*)d_in[11];
  const float* out_proj_w= (const float*)d_in[12];
  const float* fc1_w     = (const float*)d_in[13];
  const float* fc2_w     = (const float*)d_in[14];
  const float* norm_f_w  = (const float*)d_in[15];
  float* logits = (float*)d_out;
  (void)in_sizes; (void)n_in; (void)out_size; (void)ws_size;

  char* W = (char*)d_ws;
  size_t off = 0;
  auto A8 = [&](size_t bytes) { void* p = W + off; off = (off + bytes + 255) & ~(size_t)255; return p; };
  float* hbuf   = (float*)A8((size_t)1024 * 1024 * 4);
  u16*   xnormb = (u16*)  A8((size_t)1024 * 1024 * 2);
  u16*   gatedb = (u16*)  A8((size_t)1024 * 2048 * 2);
  u16*   glub   = (u16*)  A8((size_t)1024 * 4096 * 2);
  float* dtsp   = (float*)A8((size_t)1024 * 32 * 4);
  float* dag    = (float*)A8((size_t)1024 * 32 * 4);
  float* pref   = (float*)A8((size_t)1024 * 32 * 4);
  float* dacum  = (float*)A8((size_t)2048 * 4);
  float* lpart  = (float*)A8((size_t)1024 * 4);
  float* lsebuf = (float*)A8((size_t)1024 * NBLK_V * 2 * 4);
  u16*   wip    = (u16*)  A8((size_t)2 * 4352 * 1024 * 2);
  u16*   wop    = (u16*)  A8((size_t)2 * 1024 * 2048 * 2);
  u16*   wfc1   = (u16*)  A8((size_t)2 * 8192 * 1024 * 2);
  u16*   wfc2   = (u16*)  A8((size_t)2 * 1024 * 4096 * 2);
  // shared span: layer temporaries; Ebf aliases it after layers are done
  char*  span   = (char*)A8((size_t)117964800);
  float* big0   = (float*)(span);                          // 17.4 MB (1024x4256)
  float* xbc    = (float*)(span + 33554432);               // 8.5 MB
  float* yb     = (float*)(span + 33554432 + 8912896);     // 8 MB
  float* Sloc   = (float*)(span + 33554432 + 8912896 + 8388608);  // 16 MB used (32 reserved)
  float* Sin    = (float*)((char*)Sloc + 33554432);        // 16 MB used
  float* part   = Sloc;                                    // splitK slices alias (32MB = 8 slices)
  u16*   Ebf    = (u16*)span;                              // 100 MB alias (51200x1024)

  dim3 b256(256), b512(512);

  k_cvt8_pad<<<dim3((4352*1024/8 + 255)/256), b256, 0, stream>>>(
      in_proj_w, wip, 4352*1024/8, 4256*1024/8);
  k_cvt8_pad<<<dim3((4352*1024/8 + 255)/256), b256, 0, stream>>>(
      in_proj_w + (size_t)4256*1024, wip + (size_t)4352*1024, 4352*1024/8, 4256*1024/8);
  k_cvt8<<<dim3(2*1024*2048/8/256), b256, 0, stream>>>(out_proj_w, wop, 2*1024*2048/8);
  k_cvt_fc1<<<dim3(2*8192*1024/8/256), b256, 0, stream>>>(fc1_w, wfc1, 2*8192*1024/8);
  k_cvt8<<<dim3(2*1024*4096/8/256), b256, 0, stream>>>(fc2_w, wfc2, 2*1024*4096/8);

  k_ln_embed<<<1024, b256, 0, stream>>>(idx, E, norm_w, hbuf, xnormb);

  const float* nw_next[2] = { norm_w + 1024, norm_f_w };
  for (int L = 0; L < 2; ++L) {
    gemm_bf16<<<dim3(8, 34, 1), b256, 0, stream>>>(
        xnormb, wip + (size_t)L * 4352 * 1024, big0, DPROJ, 1024, 1024);
    k_convdt<<<dim3(9, 1024), b256, 0, stream>>>(
        big0, conv_w + L * CONVDIM * 4, conv_b + L * CONVDIM,
        dt_bias + L * 32, A_log + L * 32, xbc, dtsp, dag);
    k_scan_local<<<dim3(NCHUNK, 32), b256, 0, stream>>>(xbc, dtsp, dag, yb, Sloc, pref, dacum);
    k_chain<<<512, b256, 0, stream>>>(Sloc, dacum, Sin);
    k_scan_fix<<<dim3(NCHUNK, 32), b256, 0, stream>>>(xbc, pref, Sin, Dp + L * 32, yb);
    k_gated_rms<<<1024, b256, 0, stream>>>(yb, big0, gnorm_w + L * 2048, gatedb);
    gemm_bf16<<<dim3(8, 8, 4), b256, 0, stream>>>(
        gatedb, wop + (size_t)L * 1024 * 2048, part, 1024, 2048, 512);
    k_red_ln<<<1024, b256, 0, stream>>>(part, 4, hbuf, norm2_w + L * 1024, xnormb);
    gemm256<<<dim3(4, 64, 1), b512, 0, stream>>>(
        xnormb, wfc1 + (size_t)L * 8192 * 1024, nullptr, 8192, 1024,
        nullptr, 0, 64, glub);
    gemm_bf16<<<dim3(8, 8, 8), b256, 0, stream>>>(
        glub, wfc2 + (size_t)L * 1024 * 4096, part, 1024, 4096, 512);
    k_red_ln<<<1024, b256, 0, stream>>>(part, 8, hbuf, nw_next[L], xnormb);
  }

  k_cvt8_pad<<<dim3((VOCABP*1024/8 + 255)/256), b256, 0, stream>>>(
      E, Ebf, VOCABP*1024/8, VOCAB*1024/8);
  gemm256<<<dim3(4 * NBLK_V, 1, 1), b512, 0, stream>>>(
      xnormb, Ebf, logits, VOCAB, 1024, lsebuf, 1, NBLK_V, nullptr);
  k_loss_final<<<1024, b256, 0, stream>>>(lsebuf, logits, tgt, lpart);
  k_loss_mean<<<1, b256, 0, stream>>>(lpart, logits + (size_t)1024 * VOCAB);
}